// Round 1
// baseline (2306.351 us; speedup 1.0000x reference)
//
#include <hip/hip_runtime.h>
#include <math.h>

// ---------------------------------------------------------------------------
// HierarchicalDiffAttentionEncoderLayer — full FP32 pipeline (round 0).
// B=4, S=1024, D=512, H=8, DH=64, DFF=2048.
// ---------------------------------------------------------------------------

#define Bn 4
#define Sn 1024
#define DM 512
#define NH 8
#define DHd 64
#define DFF 2048

// workspace layout (in floats)
#define XN_OFF  0u            // 4096*512
#define QA_OFF  2097152u      // 4096*512   (reused as ctx)
#define KA_OFF  4194304u      // 4096*512   (reused as h)
#define QP_OFF  6291456u      // 4096*1024  (reused as mid lower half)
#define KP_OFF  10485760u     // 4096*1024  (reused as mid upper half)
#define V_OFF   14680064u     // 4096*512   (reused as hn)
#define L_OFF   16777216u     // 4096

// ---------------------------------------------------------------------------
// RMSNorm: one block per row (512 elems), 256 threads.
// ---------------------------------------------------------------------------
__global__ __launch_bounds__(256)
void rmsnorm_kernel(const float* __restrict__ x, const float* __restrict__ w,
                    float* __restrict__ out) {
    int row = blockIdx.x;
    const float* xr = x + (size_t)row * DM;
    float* orow = out + (size_t)row * DM;
    int t = threadIdx.x;
    float v0 = xr[t], v1 = xr[t + 256];
    float ss = v0 * v0 + v1 * v1;
#pragma unroll
    for (int off = 32; off; off >>= 1) ss += __shfl_xor(ss, off);
    __shared__ float red[4];
    int wid = t >> 6;
    if ((t & 63) == 0) red[wid] = ss;
    __syncthreads();
    float tot = red[0] + red[1] + red[2] + red[3];
    float rinv = rsqrtf(tot / (float)DM + 1e-5f);
    orow[t]       = v0 * rinv * w[t];
    orow[t + 256] = v1 * rinv * w[t + 256];
}

// ---------------------------------------------------------------------------
// Generic FP32 GEMM: out[M,N] = A[M,K] @ W[K,N] (+bias[N]) (+res[M,N])
// 64x64 tile, BK=16, 256 threads, 4x4 per thread.
// ---------------------------------------------------------------------------
__global__ __launch_bounds__(256)
void gemm_kernel(const float* __restrict__ A, const float* __restrict__ W,
                 const float* __restrict__ bias, const float* __restrict__ res,
                 float* __restrict__ out, int M, int N, int K) {
    __shared__ float As[16][68];   // [k][m], padded
    __shared__ float Bs[16][64];   // [k][n]
    int tid = threadIdx.x;
    int bm = blockIdx.y * 64;
    int bn = blockIdx.x * 64;
    int ty = tid >> 4, tx = tid & 15;
    int ty4 = ty << 2, tx4 = tx << 2;
    int la_m = tid >> 2;
    int la_k4 = (tid & 3) << 2;
    int lb_k = tid >> 4;
    int lb_n4 = (tid & 15) << 2;
    float acc[4][4] = {};
    for (int k0 = 0; k0 < K; k0 += 16) {
        float4 av = *(const float4*)&A[(size_t)(bm + la_m) * K + k0 + la_k4];
        As[la_k4 + 0][la_m] = av.x;
        As[la_k4 + 1][la_m] = av.y;
        As[la_k4 + 2][la_m] = av.z;
        As[la_k4 + 3][la_m] = av.w;
        *(float4*)&Bs[lb_k][lb_n4] =
            *(const float4*)&W[(size_t)(k0 + lb_k) * N + bn + lb_n4];
        __syncthreads();
#pragma unroll
        for (int k = 0; k < 16; ++k) {
            float a0 = As[k][ty4 + 0];
            float a1 = As[k][ty4 + 1];
            float a2 = As[k][ty4 + 2];
            float a3 = As[k][ty4 + 3];
            float4 bv = *(const float4*)&Bs[k][tx4];
            acc[0][0] += a0 * bv.x; acc[0][1] += a0 * bv.y; acc[0][2] += a0 * bv.z; acc[0][3] += a0 * bv.w;
            acc[1][0] += a1 * bv.x; acc[1][1] += a1 * bv.y; acc[1][2] += a1 * bv.z; acc[1][3] += a1 * bv.w;
            acc[2][0] += a2 * bv.x; acc[2][1] += a2 * bv.y; acc[2][2] += a2 * bv.z; acc[2][3] += a2 * bv.w;
            acc[3][0] += a3 * bv.x; acc[3][1] += a3 * bv.y; acc[3][2] += a3 * bv.z; acc[3][3] += a3 * bv.w;
        }
        __syncthreads();
    }
    float4 bv = bias ? *(const float4*)&bias[bn + tx4] : make_float4(0.f, 0.f, 0.f, 0.f);
#pragma unroll
    for (int i = 0; i < 4; ++i) {
        int row = bm + ty4 + i;
        float4 o;
        o.x = acc[i][0] + bv.x;
        o.y = acc[i][1] + bv.y;
        o.z = acc[i][2] + bv.z;
        o.w = acc[i][3] + bv.w;
        if (res) {
            float4 rv = *(const float4*)&res[(size_t)row * N + bn + tx4];
            o.x += rv.x; o.y += rv.y; o.z += rv.z; o.w += rv.w;
        }
        *(float4*)&out[(size_t)row * N + bn + tx4] = o;
    }
}

// ---------------------------------------------------------------------------
// SwiGLU GEMM: mid[M,N] = silu(A@Wg) * (A@Wu)
// ---------------------------------------------------------------------------
__global__ __launch_bounds__(256)
void gemm_swiglu_kernel(const float* __restrict__ A, const float* __restrict__ Wg,
                        const float* __restrict__ Wu, float* __restrict__ out,
                        int M, int N, int K) {
    __shared__ float As[16][68];
    __shared__ float Bg[16][64];
    __shared__ float Bu[16][64];
    int tid = threadIdx.x;
    int bm = blockIdx.y * 64;
    int bn = blockIdx.x * 64;
    int ty = tid >> 4, tx = tid & 15;
    int ty4 = ty << 2, tx4 = tx << 2;
    int la_m = tid >> 2;
    int la_k4 = (tid & 3) << 2;
    int lb_k = tid >> 4;
    int lb_n4 = (tid & 15) << 2;
    float accg[4][4] = {};
    float accu[4][4] = {};
    for (int k0 = 0; k0 < K; k0 += 16) {
        float4 av = *(const float4*)&A[(size_t)(bm + la_m) * K + k0 + la_k4];
        As[la_k4 + 0][la_m] = av.x;
        As[la_k4 + 1][la_m] = av.y;
        As[la_k4 + 2][la_m] = av.z;
        As[la_k4 + 3][la_m] = av.w;
        *(float4*)&Bg[lb_k][lb_n4] =
            *(const float4*)&Wg[(size_t)(k0 + lb_k) * N + bn + lb_n4];
        *(float4*)&Bu[lb_k][lb_n4] =
            *(const float4*)&Wu[(size_t)(k0 + lb_k) * N + bn + lb_n4];
        __syncthreads();
#pragma unroll
        for (int k = 0; k < 16; ++k) {
            float a0 = As[k][ty4 + 0];
            float a1 = As[k][ty4 + 1];
            float a2 = As[k][ty4 + 2];
            float a3 = As[k][ty4 + 3];
            float4 gv = *(const float4*)&Bg[k][tx4];
            float4 uv = *(const float4*)&Bu[k][tx4];
            accg[0][0] += a0 * gv.x; accg[0][1] += a0 * gv.y; accg[0][2] += a0 * gv.z; accg[0][3] += a0 * gv.w;
            accg[1][0] += a1 * gv.x; accg[1][1] += a1 * gv.y; accg[1][2] += a1 * gv.z; accg[1][3] += a1 * gv.w;
            accg[2][0] += a2 * gv.x; accg[2][1] += a2 * gv.y; accg[2][2] += a2 * gv.z; accg[2][3] += a2 * gv.w;
            accg[3][0] += a3 * gv.x; accg[3][1] += a3 * gv.y; accg[3][2] += a3 * gv.z; accg[3][3] += a3 * gv.w;
            accu[0][0] += a0 * uv.x; accu[0][1] += a0 * uv.y; accu[0][2] += a0 * uv.z; accu[0][3] += a0 * uv.w;
            accu[1][0] += a1 * uv.x; accu[1][1] += a1 * uv.y; accu[1][2] += a1 * uv.z; accu[1][3] += a1 * uv.w;
            accu[2][0] += a2 * uv.x; accu[2][1] += a2 * uv.y; accu[2][2] += a2 * uv.z; accu[2][3] += a2 * uv.w;
            accu[3][0] += a3 * uv.x; accu[3][1] += a3 * uv.y; accu[3][2] += a3 * uv.z; accu[3][3] += a3 * uv.w;
        }
        __syncthreads();
    }
#pragma unroll
    for (int i = 0; i < 4; ++i) {
        int row = bm + ty4 + i;
        float4 o;
#pragma unroll
        for (int j = 0; j < 4; ++j) {
            float g = accg[i][j];
            float u = accu[i][j];
            float sg = g / (1.f + expf(-g));
            (&o.x)[j] = sg * u;
        }
        *(float4*)&out[(size_t)row * N + bn + tx4] = o;
    }
}

// ---------------------------------------------------------------------------
// Neighbor affinity + hierarchical L: one block per batch.
// L[b,0]=0 ; L[b,i]=sum_{j<i} log(0.5*(sig(s_fwd)+sig(s_bwd)))
// ---------------------------------------------------------------------------
__global__ __launch_bounds__(256)
void affinity_kernel(const float* __restrict__ qa, const float* __restrict__ ka,
                     float* __restrict__ L) {
    int b = blockIdx.x;
    __shared__ float la[Sn - 1];
    int t = threadIdx.x;
    for (int i = t; i < Sn - 1; i += 256) {
        const float4* Qi  = (const float4*)(qa + ((size_t)(b * Sn + i)) * DM);
        const float4* Ki1 = (const float4*)(ka + ((size_t)(b * Sn + i + 1)) * DM);
        const float4* Qi1 = (const float4*)(qa + ((size_t)(b * Sn + i + 1)) * DM);
        const float4* Ki  = (const float4*)(ka + ((size_t)(b * Sn + i)) * DM);
        float sf = 0.f, sb = 0.f;
#pragma unroll 4
        for (int d = 0; d < DM / 4; ++d) {
            float4 q0 = Qi[d], k1 = Ki1[d], q1 = Qi1[d], k0 = Ki[d];
            sf += q0.x * k1.x + q0.y * k1.y + q0.z * k1.z + q0.w * k1.w;
            sb += q1.x * k0.x + q1.y * k0.y + q1.z * k0.z + q1.w * k0.w;
        }
        sf *= (1.f / 512.f);
        sb *= (1.f / 512.f);
        float a = 0.5f * (1.f / (1.f + expf(-sf)) + 1.f / (1.f + expf(-sb)));
        la[i] = logf(a);
    }
    __syncthreads();
    if (t == 0) {
        float acc = 0.f;
        L[b * Sn] = 0.f;
        for (int i = 0; i < Sn - 1; ++i) {
            acc += la[i];
            L[b * Sn + i + 1] = acc;
        }
    }
}

// ---------------------------------------------------------------------------
// Differential attention, one block (256 thr) per (b,h,q) row.
// ---------------------------------------------------------------------------
__global__ __launch_bounds__(256)
void attn_kernel(const float* __restrict__ qp, const float* __restrict__ kp,
                 const float* __restrict__ v, const float* __restrict__ L,
                 const int* __restrict__ mask, const float* __restrict__ lam_p,
                 float* __restrict__ ctx) {
    int q = blockIdx.x, h = blockIdx.y, b = blockIdx.z;
    __shared__ float q1s[64], q2s[64];
    __shared__ float comb[Sn];
    __shared__ float redA[4], redB[4];
    __shared__ float part[4][64];
    int t = threadIdx.x;
    const float* qrow = qp + ((size_t)(b * Sn + q)) * (2 * DM) + h * DHd;
    if (t < 64) q1s[t] = qrow[t];
    else if (t < 128) q2s[t - 64] = qrow[512 + (t - 64)];
    __syncthreads();

    float lam = lam_p[0];
    float Lq = L[b * Sn + q];
    const float scale = 0.125f;  // 1/sqrt(64)

    float s1v[4], s2v[4];
#pragma unroll
    for (int c = 0; c < 4; ++c) {
        int k = t + c * 256;
        float s1, s2;
        if (mask[b * Sn + k] == 0) {
            s1 = -1e9f; s2 = -1e9f;
        } else {
            const float4* kr = (const float4*)(kp + ((size_t)(b * Sn + k)) * (2 * DM) + h * DHd);
            s1 = 0.f; s2 = 0.f;
#pragma unroll
            for (int d = 0; d < 16; ++d) {
                float4 k1 = kr[d];
                float4 k2 = kr[d + 128];  // +512 floats
                s1 += q1s[d * 4 + 0] * k1.x + q1s[d * 4 + 1] * k1.y + q1s[d * 4 + 2] * k1.z + q1s[d * 4 + 3] * k1.w;
                s2 += q2s[d * 4 + 0] * k2.x + q2s[d * 4 + 1] * k2.y + q2s[d * 4 + 2] * k2.z + q2s[d * 4 + 3] * k2.w;
            }
            s1 *= scale; s2 *= scale;
        }
        s1v[c] = s1; s2v[c] = s2;
    }
    // block max
    float m1 = fmaxf(fmaxf(s1v[0], s1v[1]), fmaxf(s1v[2], s1v[3]));
    float m2 = fmaxf(fmaxf(s2v[0], s2v[1]), fmaxf(s2v[2], s2v[3]));
#pragma unroll
    for (int off = 32; off; off >>= 1) {
        m1 = fmaxf(m1, __shfl_xor(m1, off));
        m2 = fmaxf(m2, __shfl_xor(m2, off));
    }
    int wid = t >> 6;
    if ((t & 63) == 0) { redA[wid] = m1; redB[wid] = m2; }
    __syncthreads();
    m1 = fmaxf(fmaxf(redA[0], redA[1]), fmaxf(redA[2], redA[3]));
    m2 = fmaxf(fmaxf(redB[0], redB[1]), fmaxf(redB[2], redB[3]));
    __syncthreads();
    // block sum of exp
    float e1 = 0.f, e2 = 0.f;
#pragma unroll
    for (int c = 0; c < 4; ++c) {
        e1 += __expf(s1v[c] - m1);
        e2 += __expf(s2v[c] - m2);
    }
#pragma unroll
    for (int off = 32; off; off >>= 1) {
        e1 += __shfl_xor(e1, off);
        e2 += __shfl_xor(e2, off);
    }
    if ((t & 63) == 0) { redA[wid] = e1; redB[wid] = e2; }
    __syncthreads();
    float sum1 = redA[0] + redA[1] + redA[2] + redA[3];
    float sum2 = redB[0] + redB[1] + redB[2] + redB[3];
    float inv1 = 1.f / sum1, inv2 = 1.f / sum2;
#pragma unroll
    for (int c = 0; c < 4; ++c) {
        int k = t + c * 256;
        float aw1 = __expf(s1v[c] - m1) * inv1;
        float aw2 = __expf(s2v[c] - m2) * inv2;
        float C = __expf(-fabsf(Lq - L[b * Sn + k]));
        comb[k] = C * (aw1 - lam * aw2);
    }
    __syncthreads();
    // ctx[d] = sum_k comb[k] * v[k][d]
    int d = t & 63, kc = t >> 6;
    float p = 0.f;
    const float* vb = v + ((size_t)(b * Sn)) * DM + h * DHd + d;
    for (int kk = kc * 256; kk < kc * 256 + 256; ++kk)
        p += comb[kk] * vb[(size_t)kk * DM];
    part[kc][d] = p;
    __syncthreads();
    if (t < 64) {
        float r = part[0][t] + part[1][t] + part[2][t] + part[3][t];
        ctx[((size_t)(b * Sn + q)) * DM + h * DHd + t] = r;
    }
}

// ---------------------------------------------------------------------------
// GroupNorm over (d_head, S) per (b,h), in-place, x0.8 (= 1 - lambda_init).
// ---------------------------------------------------------------------------
__global__ __launch_bounds__(256)
void groupnorm_kernel(float* __restrict__ ctx, const float* __restrict__ gamma,
                      const float* __restrict__ beta) {
    int b = blockIdx.x >> 3;
    int h = blockIdx.x & 7;
    int t = threadIdx.x;
    float sum = 0.f, sq = 0.f;
    for (int i = t; i < Sn * DHd; i += 256) {
        int s = i >> 6, d = i & 63;
        float vv = ctx[((size_t)(b * Sn + s)) * DM + h * DHd + d];
        sum += vv; sq += vv * vv;
    }
#pragma unroll
    for (int off = 32; off; off >>= 1) {
        sum += __shfl_xor(sum, off);
        sq  += __shfl_xor(sq, off);
    }
    __shared__ float rs[4], rq[4];
    int wid = t >> 6;
    if ((t & 63) == 0) { rs[wid] = sum; rq[wid] = sq; }
    __syncthreads();
    float Stot = rs[0] + rs[1] + rs[2] + rs[3];
    float Qtot = rq[0] + rq[1] + rq[2] + rq[3];
    const float n = (float)(Sn * DHd);
    float mean = Stot / n;
    float var = Qtot / n - mean * mean;
    float rinv = rsqrtf(var + 1e-5f);
    for (int i = t; i < Sn * DHd; i += 256) {
        int s = i >> 6, d = i & 63;
        size_t off_ = ((size_t)(b * Sn + s)) * DM + h * DHd + d;
        int c = h * DHd + d;
        float vv = ctx[off_];
        ctx[off_] = ((vv - mean) * rinv * gamma[c] + beta[c]) * 0.8f;
    }
}

// ---------------------------------------------------------------------------
extern "C" void kernel_launch(void* const* d_in, const int* in_sizes, int n_in,
                              void* d_out, int out_size, void* d_ws, size_t ws_size,
                              hipStream_t stream) {
    const float* x       = (const float*)d_in[0];
    const int*   mask    = (const int*)d_in[1];
    const float* lam     = (const float*)d_in[2];
    const float* wq_w    = (const float*)d_in[3];
    const float* wq_b    = (const float*)d_in[4];
    const float* wk_w    = (const float*)d_in[5];
    const float* wk_b    = (const float*)d_in[6];
    const float* wv_w    = (const float*)d_in[7];
    const float* wv_b    = (const float*)d_in[8];
    const float* out_w   = (const float*)d_in[9];
    const float* out_b   = (const float*)d_in[10];
    const float* gn_gamma= (const float*)d_in[11];
    const float* gn_beta = (const float*)d_in[12];
    const float* aq_w    = (const float*)d_in[13];
    const float* aq_b    = (const float*)d_in[14];
    const float* ak_w    = (const float*)d_in[15];
    const float* ak_b    = (const float*)d_in[16];
    const float* wg_w    = (const float*)d_in[17];
    const float* w1_w    = (const float*)d_in[18];
    const float* w2_w    = (const float*)d_in[19];
    const float* norm1_w = (const float*)d_in[20];
    const float* norm2_w = (const float*)d_in[21];

    float* ws  = (float*)d_ws;
    float* xn  = ws + XN_OFF;
    float* qa  = ws + QA_OFF;
    float* ka  = ws + KA_OFF;
    float* qp  = ws + QP_OFF;
    float* kp  = ws + KP_OFF;
    float* v   = ws + V_OFF;
    float* Lb  = ws + L_OFF;
    float* ctx = qa;        // reuse after L computed
    float* h   = ka;        // reuse after L computed
    float* hn  = v;         // reuse after attention
    float* mid = qp;        // reuse qp+kp (32MB) after attention
    float* outp = (float*)d_out;

    const int M = Bn * Sn;  // 4096

    rmsnorm_kernel<<<M, 256, 0, stream>>>(x, norm1_w, xn);

    dim3 g512(DM / 64, M / 64);
    dim3 g1024(2 * DM / 64, M / 64);
    dim3 g2048(DFF / 64, M / 64);

    gemm_kernel<<<g512, 256, 0, stream>>>(xn, aq_w, aq_b, nullptr, qa, M, DM, DM);
    gemm_kernel<<<g512, 256, 0, stream>>>(xn, ak_w, ak_b, nullptr, ka, M, DM, DM);
    affinity_kernel<<<Bn, 256, 0, stream>>>(qa, ka, Lb);

    gemm_kernel<<<g1024, 256, 0, stream>>>(xn, wq_w, wq_b, nullptr, qp, M, 2 * DM, DM);
    gemm_kernel<<<g1024, 256, 0, stream>>>(xn, wk_w, wk_b, nullptr, kp, M, 2 * DM, DM);
    gemm_kernel<<<g512, 256, 0, stream>>>(xn, wv_w, wv_b, nullptr, v, M, DM, DM);

    dim3 ga(Sn, NH, Bn);
    attn_kernel<<<ga, 256, 0, stream>>>(qp, kp, v, Lb, mask, lam, ctx);

    groupnorm_kernel<<<Bn * NH, 256, 0, stream>>>(ctx, gn_gamma, gn_beta);

    gemm_kernel<<<g512, 256, 0, stream>>>(ctx, out_w, out_b, x, h, M, DM, DM);

    rmsnorm_kernel<<<M, 256, 0, stream>>>(h, norm2_w, hn);

    gemm_swiglu_kernel<<<g2048, 256, 0, stream>>>(hn, wg_w, w1_w, mid, M, DFF, DM);

    gemm_kernel<<<g512, 256, 0, stream>>>(mid, w2_w, nullptr, h, outp, M, DM, DFF);
}

// Round 4
// 475.078 us; speedup vs baseline: 4.8547x; 4.8547x over previous
//
#include <hip/hip_runtime.h>
#include <math.h>

#define Bn 4
#define Sn 1024
#define DM 512
#define NH 8
#define DFF 2048

typedef __attribute__((ext_vector_type(8))) __bf16 bf16x8;
typedef __attribute__((ext_vector_type(4))) __bf16 bf16x4;
typedef __attribute__((ext_vector_type(2))) __bf16 bf16x2;
typedef __attribute__((ext_vector_type(4))) float f32x4;

#define MB (1u<<20)

// ---------------------------------------------------------------------------
// transpose + f32->bf16: wT[n][k] = w[k][n]
// ---------------------------------------------------------------------------
__global__ __launch_bounds__(256)
void transpose_kernel(const float* __restrict__ w, __bf16* __restrict__ wT,
                      int K, int N) {
    __shared__ float tile[32][33];
    int n0 = blockIdx.x * 32, k0 = blockIdx.y * 32;
    int tx = threadIdx.x, ty = threadIdx.y;  // 32 x 8
#pragma unroll
    for (int i = 0; i < 4; ++i)
        tile[ty + 8 * i][tx] = w[(size_t)(k0 + ty + 8 * i) * N + n0 + tx];
    __syncthreads();
#pragma unroll
    for (int i = 0; i < 4; ++i)
        wT[(size_t)(n0 + ty + 8 * i) * K + k0 + tx] = (__bf16)tile[tx][ty + 8 * i];
}

// ---------------------------------------------------------------------------
// RMSNorm: f32 in -> bf16 out. one block per row.
// ---------------------------------------------------------------------------
__global__ __launch_bounds__(256)
void rmsnorm_kernel(const float* __restrict__ x, const float* __restrict__ w,
                    __bf16* __restrict__ out) {
    int row = blockIdx.x;
    const float* xr = x + (size_t)row * DM;
    int t = threadIdx.x;
    float2 v = *(const float2*)&xr[2 * t];
    float ss = v.x * v.x + v.y * v.y;
#pragma unroll
    for (int off = 32; off; off >>= 1) ss += __shfl_xor(ss, off);
    __shared__ float red[4];
    int wid = t >> 6;
    if ((t & 63) == 0) red[wid] = ss;
    __syncthreads();
    float tot = red[0] + red[1] + red[2] + red[3];
    float rinv = rsqrtf(tot / (float)DM + 1e-5f);
    bf16x2 o;
    o[0] = (__bf16)(v.x * rinv * w[2 * t]);
    o[1] = (__bf16)(v.y * rinv * w[2 * t + 1]);
    *(bf16x2*)&out[(size_t)row * DM + 2 * t] = o;
}

// ---------------------------------------------------------------------------
// bf16 MFMA GEMM: out[M,N] = A[M,K] @ BT[N,K]^T (+bias) (+res, f32 out)
// BN=128 fixed. 256 threads, 4 waves 2x2. BK=32.
// EPI 0: bf16 out + bias.  EPI 1: f32 out + bias? + res?
// ---------------------------------------------------------------------------
template<int BM, int EPI>
__global__ __launch_bounds__(256)
void gemm_bf16(const __bf16* __restrict__ A, const __bf16* __restrict__ BT,
               const float* __restrict__ bias, const float* __restrict__ res,
               void* __restrict__ out, int M, int N, int K) {
    __shared__ __bf16 As[BM][32];
    __shared__ __bf16 Bs[128][32];
    const int t = threadIdx.x;
    const int w = t >> 6, l = t & 63, c = l & 15, g = l >> 4;
    const int wr = w >> 1, wc = w & 1;
    const int bm = blockIdx.y * BM, bn = blockIdx.x * 128;
    constexpr int HM = BM / 2;
    constexpr int WM = BM / 32;
    f32x4 acc[WM][4];
#pragma unroll
    for (int m = 0; m < WM; ++m)
#pragma unroll
        for (int n = 0; n < 4; ++n) acc[m][n] = (f32x4){0.f, 0.f, 0.f, 0.f};
    const int row = t >> 2, kg = t & 3;
    const __bf16* Ap = A + (size_t)(bm + row) * K + kg * 8;
    const __bf16* Bp = BT + (size_t)(bn + row) * K + kg * 8;
    for (int k0 = 0; k0 < K; k0 += 32) {
        bf16x8 a0 = *(const bf16x8*)(Ap + k0);
        bf16x8 a1;
        if constexpr (BM == 128) a1 = *(const bf16x8*)(Ap + (size_t)64 * K + k0);
        bf16x8 b0 = *(const bf16x8*)(Bp + k0);
        bf16x8 b1 = *(const bf16x8*)(Bp + (size_t)64 * K + k0);
        *(bf16x8*)&As[row][kg * 8] = a0;
        if constexpr (BM == 128) *(bf16x8*)&As[row + 64][kg * 8] = a1;
        *(bf16x8*)&Bs[row][kg * 8] = b0;
        *(bf16x8*)&Bs[row + 64][kg * 8] = b1;
        __syncthreads();
        bf16x8 af[WM], bf_[4];
#pragma unroll
        for (int m = 0; m < WM; ++m) af[m] = *(const bf16x8*)&As[wr * HM + m * 16 + c][g * 8];
#pragma unroll
        for (int n = 0; n < 4; ++n) bf_[n] = *(const bf16x8*)&Bs[wc * 64 + n * 16 + c][g * 8];
#pragma unroll
        for (int m = 0; m < WM; ++m)
#pragma unroll
            for (int n = 0; n < 4; ++n)
                acc[m][n] = __builtin_amdgcn_mfma_f32_16x16x32_bf16(af[m], bf_[n], acc[m][n], 0, 0, 0);
        __syncthreads();
    }
#pragma unroll
    for (int m = 0; m < WM; ++m)
#pragma unroll
        for (int n = 0; n < 4; ++n) {
            int rowb = bm + wr * HM + m * 16 + 4 * g;
            int col = bn + wc * 64 + n * 16 + c;
            float bv = bias ? bias[col] : 0.f;
#pragma unroll
            for (int r = 0; r < 4; ++r) {
                size_t idx = (size_t)(rowb + r) * N + col;
                float val = acc[m][n][r] + bv;
                if constexpr (EPI == 0) {
                    ((__bf16*)out)[idx] = (__bf16)val;
                } else {
                    if (res) val += res[idx];
                    ((float*)out)[idx] = val;
                }
            }
        }
}

// ---------------------------------------------------------------------------
// SwiGLU GEMM: mid = silu(A@WgT^T) * (A@WuT^T), bf16 out. BM=128.
// ---------------------------------------------------------------------------
__global__ __launch_bounds__(256)
void gemm_swiglu(const __bf16* __restrict__ A, const __bf16* __restrict__ GT,
                 const __bf16* __restrict__ UT, __bf16* __restrict__ out,
                 int M, int N, int K) {
    __shared__ __bf16 As[128][32];
    __shared__ __bf16 Gs[128][32];
    __shared__ __bf16 Us[128][32];
    const int t = threadIdx.x;
    const int w = t >> 6, l = t & 63, c = l & 15, g = l >> 4;
    const int wr = w >> 1, wc = w & 1;
    const int bm = blockIdx.y * 128, bn = blockIdx.x * 128;
    f32x4 accg[4][4], accu[4][4];
#pragma unroll
    for (int m = 0; m < 4; ++m)
#pragma unroll
        for (int n = 0; n < 4; ++n) {
            accg[m][n] = (f32x4){0.f, 0.f, 0.f, 0.f};
            accu[m][n] = (f32x4){0.f, 0.f, 0.f, 0.f};
        }
    const int row = t >> 2, kg = t & 3;
    const __bf16* Ap = A + (size_t)(bm + row) * K + kg * 8;
    const __bf16* Gp = GT + (size_t)(bn + row) * K + kg * 8;
    const __bf16* Up = UT + (size_t)(bn + row) * K + kg * 8;
    for (int k0 = 0; k0 < K; k0 += 32) {
        bf16x8 a0 = *(const bf16x8*)(Ap + k0);
        bf16x8 a1 = *(const bf16x8*)(Ap + (size_t)64 * K + k0);
        bf16x8 g0 = *(const bf16x8*)(Gp + k0);
        bf16x8 g1 = *(const bf16x8*)(Gp + (size_t)64 * K + k0);
        bf16x8 u0 = *(const bf16x8*)(Up + k0);
        bf16x8 u1 = *(const bf16x8*)(Up + (size_t)64 * K + k0);
        *(bf16x8*)&As[row][kg * 8] = a0;
        *(bf16x8*)&As[row + 64][kg * 8] = a1;
        *(bf16x8*)&Gs[row][kg * 8] = g0;
        *(bf16x8*)&Gs[row + 64][kg * 8] = g1;
        *(bf16x8*)&Us[row][kg * 8] = u0;
        *(bf16x8*)&Us[row + 64][kg * 8] = u1;
        __syncthreads();
        bf16x8 af[4], gf[4], uf[4];
#pragma unroll
        for (int m = 0; m < 4; ++m) af[m] = *(const bf16x8*)&As[wr * 64 + m * 16 + c][g * 8];
#pragma unroll
        for (int n = 0; n < 4; ++n) {
            gf[n] = *(const bf16x8*)&Gs[wc * 64 + n * 16 + c][g * 8];
            uf[n] = *(const bf16x8*)&Us[wc * 64 + n * 16 + c][g * 8];
        }
#pragma unroll
        for (int m = 0; m < 4; ++m)
#pragma unroll
            for (int n = 0; n < 4; ++n) {
                accg[m][n] = __builtin_amdgcn_mfma_f32_16x16x32_bf16(af[m], gf[n], accg[m][n], 0, 0, 0);
                accu[m][n] = __builtin_amdgcn_mfma_f32_16x16x32_bf16(af[m], uf[n], accu[m][n], 0, 0, 0);
            }
        __syncthreads();
    }
#pragma unroll
    for (int m = 0; m < 4; ++m)
#pragma unroll
        for (int n = 0; n < 4; ++n) {
            int rowb = bm + wr * 64 + m * 16 + 4 * g;
            int col = bn + wc * 64 + n * 16 + c;
#pragma unroll
            for (int r = 0; r < 4; ++r) {
                float gv = accg[m][n][r];
                float uv = accu[m][n][r];
                float sg = gv / (1.f + __expf(-gv));
                out[(size_t)(rowb + r) * N + col] = (__bf16)(sg * uv);
            }
        }
}

// ---------------------------------------------------------------------------
// neighbor affinity log a  (from bf16 Q,K)
// ---------------------------------------------------------------------------
__global__ __launch_bounds__(256)
void affinity_dots(const __bf16* __restrict__ qa, const __bf16* __restrict__ ka,
                   float* __restrict__ la) {
    int i = blockIdx.x * 256 + threadIdx.x;
    int b = blockIdx.y;
    if (i >= Sn - 1) { la[b * Sn + i] = 0.f; return; }
    const __bf16* Qi = qa + (size_t)(b * Sn + i) * DM;
    const __bf16* Ki = ka + (size_t)(b * Sn + i) * DM;
    float sf = 0.f, sb = 0.f;
#pragma unroll 4
    for (int d = 0; d < DM / 8; ++d) {
        bf16x8 q0 = *(const bf16x8*)(Qi + d * 8);
        bf16x8 q1 = *(const bf16x8*)(Qi + DM + d * 8);
        bf16x8 k0 = *(const bf16x8*)(Ki + d * 8);
        bf16x8 k1 = *(const bf16x8*)(Ki + DM + d * 8);
#pragma unroll
        for (int j = 0; j < 8; ++j) {
            sf += (float)q0[j] * (float)k1[j];
            sb += (float)q1[j] * (float)k0[j];
        }
    }
    sf *= (1.f / 512.f);
    sb *= (1.f / 512.f);
    float a = 0.5f * (1.f / (1.f + __expf(-sf)) + 1.f / (1.f + __expf(-sb)));
    la[b * Sn + i] = __logf(a);
}

// inclusive-scan of log-a -> L. one block (256 thr) per batch.
__global__ __launch_bounds__(256)
void scan_kernel(const float* __restrict__ la, float* __restrict__ L) {
    int b = blockIdx.x, j = threadIdx.x;
    __shared__ float sc[256];
    float4 v = *(const float4*)&la[b * Sn + 4 * j];
    float s0 = v.x, s1 = s0 + v.y, s2 = s1 + v.z, s3 = s2 + v.w;
    sc[j] = s3;
    __syncthreads();
    for (int off = 1; off < 256; off <<= 1) {
        float add = (j >= off) ? sc[j - off] : 0.f;
        __syncthreads();
        sc[j] += add;
        __syncthreads();
    }
    float base = sc[j] - s3;
    if (j == 0) L[b * Sn] = 0.f;
    L[b * Sn + 4 * j + 1] = base + s0;
    L[b * Sn + 4 * j + 2] = base + s1;
    L[b * Sn + 4 * j + 3] = base + s2;
    if (4 * j + 4 < Sn) L[b * Sn + 4 * j + 4] = base + s3;
}

// ---------------------------------------------------------------------------
// Flash-style differential attention with hierarchy mask. bf16 MFMA.
// Block: 256 thr (4 waves), 64 q-rows per block, 64-k tiles. Swapped QK.
// ---------------------------------------------------------------------------
__global__ __launch_bounds__(256)
void attn_mfma(const __bf16* __restrict__ qp, const __bf16* __restrict__ kp,
               const __bf16* __restrict__ v, const float* __restrict__ L,
               const int* __restrict__ mask, const float* __restrict__ lam_p,
               float* __restrict__ ctx) {
    const int qb = blockIdx.x, h = blockIdx.y, b = blockIdx.z;
    const int t = threadIdx.x;
    const int w = t >> 6, l = t & 63, c = l & 15, g = l >> 4;
    __shared__ __bf16 Klds[2][64][72];
    __shared__ __bf16 Vt[64][72];
    __shared__ __bf16 Plds[2][64][72];
    __shared__ float Lk_s[64];
    __shared__ float msk_s[64];
    __shared__ float fs_s[2][64];
    __shared__ float ls_s[2][64];
    const int q0 = qb * 64;
    const int qg = q0 + 16 * w + c;
    float Lq = L[b * Sn + qg];
    float lam = lam_p[0];
    bf16x8 qf[2][2];
#pragma unroll
    for (int mat = 0; mat < 2; ++mat)
#pragma unroll
        for (int dh = 0; dh < 2; ++dh)
            qf[mat][dh] = *(const bf16x8*)(qp + (size_t)(b * Sn + qg) * 1024 + mat * 512 + h * 64 + dh * 32 + g * 8);
    f32x4 O[2][4];
#pragma unroll
    for (int mat = 0; mat < 2; ++mat)
#pragma unroll
        for (int nd = 0; nd < 4; ++nd) O[mat][nd] = (f32x4){0.f, 0.f, 0.f, 0.f};
    float m_run[2] = {-INFINITY, -INFINITY};
    float l_run[2] = {0.f, 0.f};

    for (int kt = 0; kt < 16; ++kt) {
        // ---- stage K (2 mats), V^T, mask, L ----
#pragma unroll
        for (int rep = 0; rep < 4; ++rep) {
            int ch = rep * 256 + t;
            int mat = ch >> 9, rem = ch & 511;
            int krow = rem >> 3, dg = rem & 7;
            bf16x8 val = *(const bf16x8*)(kp + (size_t)(b * Sn + kt * 64 + krow) * 1024 + mat * 512 + h * 64 + dg * 8);
            *(bf16x8*)&Klds[mat][krow][dg * 8] = val;
        }
#pragma unroll
        for (int rep = 0; rep < 2; ++rep) {
            int ch = rep * 256 + t;
            int k = ch & 63, dg = ch >> 6;
            bf16x8 val = *(const bf16x8*)(v + (size_t)(b * Sn + kt * 64 + k) * 512 + h * 64 + dg * 8);
#pragma unroll
            for (int j = 0; j < 8; ++j) Vt[dg * 8 + j][k] = val[j];
        }
        if (t < 64) {
            Lk_s[t] = L[b * Sn + kt * 64 + t];
            msk_s[t] = (float)mask[b * Sn + kt * 64 + t];
        }
        __syncthreads();
        // ---- QK^T (swapped: S^T = K.Q^T), softmax update, P = C*e ----
#pragma unroll
        for (int mat = 0; mat < 2; ++mat) {
            f32x4 s[4];
#pragma unroll
            for (int kf = 0; kf < 4; ++kf) {
                f32x4 a = (f32x4){0.f, 0.f, 0.f, 0.f};
#pragma unroll
                for (int dh = 0; dh < 2; ++dh) {
                    bf16x8 kfr = *(const bf16x8*)&Klds[mat][kf * 16 + c][dh * 32 + g * 8];
                    a = __builtin_amdgcn_mfma_f32_16x16x32_bf16(kfr, qf[mat][dh], a, 0, 0, 0);
                }
                s[kf] = a;
            }
            float tm = -INFINITY;
#pragma unroll
            for (int kf = 0; kf < 4; ++kf)
#pragma unroll
                for (int r = 0; r < 4; ++r) {
                    int kk = kf * 16 + 4 * g + r;
                    float sv = (msk_s[kk] == 0.f) ? -1e9f : s[kf][r] * 0.125f;
                    s[kf][r] = sv;
                    tm = fmaxf(tm, sv);
                }
            tm = fmaxf(tm, __shfl_xor(tm, 16));
            tm = fmaxf(tm, __shfl_xor(tm, 32));
            float mn = fmaxf(m_run[mat], tm);
            float f = __expf(m_run[mat] - mn);
            m_run[mat] = mn;
            if (g == 0) fs_s[mat][16 * w + c] = f;
            float es = 0.f;
#pragma unroll
            for (int kf = 0; kf < 4; ++kf) {
                bf16x4 pk;
#pragma unroll
                for (int r = 0; r < 4; ++r) {
                    float ev = __expf(s[kf][r] - mn);
                    es += ev;
                    int kk = kf * 16 + 4 * g + r;
                    float C = __expf(-fabsf(Lq - Lk_s[kk]));
                    pk[r] = (__bf16)(ev * C);
                }
                *(bf16x4*)&Plds[mat][16 * w + c][kf * 16 + 4 * g] = pk;
            }
            es += __shfl_xor(es, 16);
            es += __shfl_xor(es, 32);
            l_run[mat] = l_run[mat] * f + es;
        }
        __syncthreads();
        // ---- PV: O = O*f + P.V ----
#pragma unroll
        for (int mat = 0; mat < 2; ++mat) {
            f32x4 fv = *(const f32x4*)&fs_s[mat][16 * w + 4 * g];
#pragma unroll
            for (int nd = 0; nd < 4; ++nd) O[mat][nd] *= fv;
#pragma unroll
            for (int kh = 0; kh < 2; ++kh) {
                bf16x8 pa = *(const bf16x8*)&Plds[mat][16 * w + c][kh * 32 + g * 8];
#pragma unroll
                for (int nd = 0; nd < 4; ++nd) {
                    bf16x8 vb = *(const bf16x8*)&Vt[nd * 16 + c][kh * 32 + g * 8];
                    O[mat][nd] = __builtin_amdgcn_mfma_f32_16x16x32_bf16(pa, vb, O[mat][nd], 0, 0, 0);
                }
            }
        }
        __syncthreads();
    }
    if (g == 0) {
        ls_s[0][16 * w + c] = l_run[0];
        ls_s[1][16 * w + c] = l_run[1];
    }
    __syncthreads();
    f32x4 l1 = *(const f32x4*)&ls_s[0][16 * w + 4 * g];
    f32x4 l2 = *(const f32x4*)&ls_s[1][16 * w + 4 * g];
#pragma unroll
    for (int nd = 0; nd < 4; ++nd)
#pragma unroll
        for (int r = 0; r < 4; ++r) {
            float val = O[0][nd][r] / l1[r] - lam * (O[1][nd][r] / l2[r]);
            int q = q0 + 16 * w + 4 * g + r;
            ctx[(size_t)(b * Sn + q) * DM + h * 64 + nd * 16 + c] = val;
        }
}

// ---------------------------------------------------------------------------
// GroupNorm over (d_head,S) per (b,h): ctx f32 -> bf16, x0.8
// ---------------------------------------------------------------------------
__global__ __launch_bounds__(256)
void groupnorm_kernel(const float* __restrict__ ctx, const float* __restrict__ gamma,
                      const float* __restrict__ beta, __bf16* __restrict__ out) {
    int b = blockIdx.x >> 3;
    int h = blockIdx.x & 7;
    int t = threadIdx.x;
    float sum = 0.f, sq = 0.f;
    for (int i = t; i < Sn * 32; i += 256) {
        int s = i >> 5, dp = (i & 31) * 2;
        float2 vv = *(const float2*)&ctx[(size_t)(b * Sn + s) * DM + h * 64 + dp];
        sum += vv.x + vv.y;
        sq += vv.x * vv.x + vv.y * vv.y;
    }
#pragma unroll
    for (int off = 32; off; off >>= 1) {
        sum += __shfl_xor(sum, off);
        sq += __shfl_xor(sq, off);
    }
    __shared__ float rs[4], rq[4];
    int wid = t >> 6;
    if ((t & 63) == 0) { rs[wid] = sum; rq[wid] = sq; }
    __syncthreads();
    float Stot = rs[0] + rs[1] + rs[2] + rs[3];
    float Qtot = rq[0] + rq[1] + rq[2] + rq[3];
    const float n = (float)(Sn * 64);
    float mean = Stot / n;
    float var = Qtot / n - mean * mean;
    float rinv = rsqrtf(var + 1e-5f);
    for (int i = t; i < Sn * 32; i += 256) {
        int s = i >> 5, dp = (i & 31) * 2;
        size_t off_ = (size_t)(b * Sn + s) * DM + h * 64 + dp;
        int ch = h * 64 + dp;
        float2 vv = *(const float2*)&ctx[off_];
        bf16x2 o;
        o[0] = (__bf16)(((vv.x - mean) * rinv * gamma[ch] + beta[ch]) * 0.8f);
        o[1] = (__bf16)(((vv.y - mean) * rinv * gamma[ch + 1] + beta[ch + 1]) * 0.8f);
        *(bf16x2*)&out[off_] = o;
    }
}

// ---------------------------------------------------------------------------
extern "C" void kernel_launch(void* const* d_in, const int* in_sizes, int n_in,
                              void* d_out, int out_size, void* d_ws, size_t ws_size,
                              hipStream_t stream) {
    const float* x        = (const float*)d_in[0];
    const int*   mask     = (const int*)d_in[1];
    const float* lam      = (const float*)d_in[2];
    const float* wq_w     = (const float*)d_in[3];
    const float* wq_b     = (const float*)d_in[4];
    const float* wk_w     = (const float*)d_in[5];
    const float* wk_b     = (const float*)d_in[6];
    const float* wv_w     = (const float*)d_in[7];
    const float* wv_b     = (const float*)d_in[8];
    const float* out_w    = (const float*)d_in[9];
    const float* out_b    = (const float*)d_in[10];
    const float* gn_gamma = (const float*)d_in[11];
    const float* gn_beta  = (const float*)d_in[12];
    const float* aq_w     = (const float*)d_in[13];
    const float* aq_b     = (const float*)d_in[14];
    const float* ak_w     = (const float*)d_in[15];
    const float* ak_b     = (const float*)d_in[16];
    const float* wg_w     = (const float*)d_in[17];
    const float* w1_w     = (const float*)d_in[18];
    const float* w2_w     = (const float*)d_in[19];
    const float* norm1_w  = (const float*)d_in[20];
    const float* norm2_w  = (const float*)d_in[21];

    char* ws = (char*)d_ws;
    __bf16* aqT = (__bf16*)(ws + 0);
    __bf16* akT = (__bf16*)(ws + 512 * 1024);
    __bf16* wvT = (__bf16*)(ws + 1 * MB);
    __bf16* outT = (__bf16*)(ws + 3 * MB / 2);
    __bf16* wqT = (__bf16*)(ws + 2 * MB);
    __bf16* wkT = (__bf16*)(ws + 3 * MB);
    __bf16* wgT = (__bf16*)(ws + 4 * MB);
    __bf16* w1T = (__bf16*)(ws + 6 * MB);
    __bf16* w2T = (__bf16*)(ws + 8 * MB);
    __bf16* xn  = (__bf16*)(ws + 10 * MB);
    __bf16* qa  = (__bf16*)(ws + 14 * MB);
    __bf16* ka  = (__bf16*)(ws + 18 * MB);
    __bf16* qp  = (__bf16*)(ws + 22 * MB);
    __bf16* kp  = (__bf16*)(ws + 30 * MB);
    __bf16* v   = (__bf16*)(ws + 38 * MB);
    float*  la  = (float*)(ws + 42 * MB);
    float*  Lb  = (float*)(ws + 42 * MB + 64 * 1024);
    float*  ctx = (float*)(ws + 43 * MB);
    __bf16* ctxb = (__bf16*)(ws + 51 * MB);
    float*  h   = (float*)(ws + 55 * MB);
    __bf16* hn  = (__bf16*)(ws + 14 * MB);  // reuse qa
    __bf16* mid = (__bf16*)(ws + 22 * MB);  // reuse qp+kp
    float*  outp = (float*)d_out;

    const int M = Bn * Sn;  // 4096
    dim3 tb(32, 8);

    // weight transposes (f32 -> bf16, [K][N] -> [N][K])
    transpose_kernel<<<dim3(512 / 32, 512 / 32), tb, 0, stream>>>(aq_w, aqT, 512, 512);
    transpose_kernel<<<dim3(512 / 32, 512 / 32), tb, 0, stream>>>(ak_w, akT, 512, 512);
    transpose_kernel<<<dim3(512 / 32, 512 / 32), tb, 0, stream>>>(wv_w, wvT, 512, 512);
    transpose_kernel<<<dim3(512 / 32, 512 / 32), tb, 0, stream>>>(out_w, outT, 512, 512);
    transpose_kernel<<<dim3(1024 / 32, 512 / 32), tb, 0, stream>>>(wq_w, wqT, 512, 1024);
    transpose_kernel<<<dim3(1024 / 32, 512 / 32), tb, 0, stream>>>(wk_w, wkT, 512, 1024);
    transpose_kernel<<<dim3(2048 / 32, 512 / 32), tb, 0, stream>>>(wg_w, wgT, 512, 2048);
    transpose_kernel<<<dim3(2048 / 32, 512 / 32), tb, 0, stream>>>(w1_w, w1T, 512, 2048);
    transpose_kernel<<<dim3(512 / 32, 2048 / 32), tb, 0, stream>>>(w2_w, w2T, 2048, 512);

    rmsnorm_kernel<<<M, 256, 0, stream>>>(x, norm1_w, xn);

    gemm_bf16<64, 0><<<dim3(4, 64), 256, 0, stream>>>(xn, aqT, aq_b, nullptr, qa, M, 512, 512);
    gemm_bf16<64, 0><<<dim3(4, 64), 256, 0, stream>>>(xn, akT, ak_b, nullptr, ka, M, 512, 512);
    affinity_dots<<<dim3(4, 4), 256, 0, stream>>>(qa, ka, la);
    scan_kernel<<<Bn, 256, 0, stream>>>(la, Lb);

    gemm_bf16<128, 0><<<dim3(8, 32), 256, 0, stream>>>(xn, wqT, wq_b, nullptr, qp, M, 1024, 512);
    gemm_bf16<128, 0><<<dim3(8, 32), 256, 0, stream>>>(xn, wkT, wk_b, nullptr, kp, M, 1024, 512);
    gemm_bf16<64, 0><<<dim3(4, 64), 256, 0, stream>>>(xn, wvT, wv_b, nullptr, v, M, 512, 512);

    attn_mfma<<<dim3(16, NH, Bn), 256, 0, stream>>>(qp, kp, v, Lb, mask, lam, ctx);

    groupnorm_kernel<<<Bn * NH, 256, 0, stream>>>(ctx, gn_gamma, gn_beta, ctxb);

    gemm_bf16<64, 1><<<dim3(4, 64), 256, 0, stream>>>(ctxb, outT, out_b, x, h, M, 512, 512);

    rmsnorm_kernel<<<M, 256, 0, stream>>>(h, norm2_w, hn);

    gemm_swiglu<<<dim3(16, 32), 256, 0, stream>>>(hn, wgT, w1T, mid, M, 2048, 512);

    gemm_bf16<64, 1><<<dim3(4, 64), 256, 0, stream>>>(mid, w2T, nullptr, h, outp, M, 512, 2048);
}

// Round 5
// 366.132 us; speedup vs baseline: 6.2992x; 1.2976x over previous
//
#include <hip/hip_runtime.h>
#include <math.h>

#define Bn 4
#define Sn 1024
#define DM 512
#define NH 8
#define DFF 2048
#define QKVN 2560

typedef __attribute__((ext_vector_type(8))) __bf16 bf16x8;
typedef __attribute__((ext_vector_type(2))) __bf16 bf16x2;
typedef __attribute__((ext_vector_type(4))) float f32x4;

#define MB (1u<<20)

// async global->LDS, 16B per lane. dest = wave-uniform base + lane*16.
__device__ __forceinline__ void gl_lds16(const void* g, void* l) {
    __builtin_amdgcn_global_load_lds(
        (const __attribute__((address_space(1))) void*)g,
        (__attribute__((address_space(3))) void*)l, 16, 0, 0);
}

// ---------------------------------------------------------------------------
// batched transpose + f32->bf16: dst[n][k] = src[k][n]
// ---------------------------------------------------------------------------
struct TransBatch { const float* src[4]; __bf16* dst[4]; };

__global__ __launch_bounds__(256)
void transpose_kernel(TransBatch tb, int K, int N) {
    const float* w = tb.src[blockIdx.z];
    __bf16* wT = tb.dst[blockIdx.z];
    __shared__ float tile[32][33];
    int n0 = blockIdx.x * 32, k0 = blockIdx.y * 32;
    int tx = threadIdx.x, ty = threadIdx.y;  // 32 x 8
#pragma unroll
    for (int i = 0; i < 4; ++i)
        tile[ty + 8 * i][tx] = w[(size_t)(k0 + ty + 8 * i) * N + n0 + tx];
    __syncthreads();
#pragma unroll
    for (int i = 0; i < 4; ++i)
        wT[(size_t)(n0 + ty + 8 * i) * K + k0 + tx] = (__bf16)tile[tx][ty + 8 * i];
}

// pack biases: aqk_b[1024] = aq_b|ak_b ; qkv_b[2560] = wq_b|wk_b|wv_b
__global__ __launch_bounds__(256)
void pack_biases(const float* aq_b, const float* ak_b, const float* wq_b,
                 const float* wk_b, const float* wv_b,
                 float* aqk_b, float* qkv_b) {
    int t = blockIdx.x * 256 + threadIdx.x;
    if (t < 512) aqk_b[t] = aq_b[t];
    else if (t < 1024) aqk_b[t] = ak_b[t - 512];
    else if (t < 2048) qkv_b[t - 1024] = wq_b[t - 1024];
    else if (t < 3072) qkv_b[1024 + t - 2048] = wk_b[t - 2048];
    else if (t < 3584) qkv_b[2048 + t - 3072] = wv_b[t - 3072];
}

// ---------------------------------------------------------------------------
// RMSNorm: f32 in -> bf16 out. one block per row.
// ---------------------------------------------------------------------------
__global__ __launch_bounds__(256)
void rmsnorm_kernel(const float* __restrict__ x, const float* __restrict__ w,
                    __bf16* __restrict__ out) {
    int row = blockIdx.x;
    const float* xr = x + (size_t)row * DM;
    int t = threadIdx.x;
    float2 v = *(const float2*)&xr[2 * t];
    float ss = v.x * v.x + v.y * v.y;
#pragma unroll
    for (int off = 32; off; off >>= 1) ss += __shfl_xor(ss, off);
    __shared__ float red[4];
    int wid = t >> 6;
    if ((t & 63) == 0) red[wid] = ss;
    __syncthreads();
    float tot = red[0] + red[1] + red[2] + red[3];
    float rinv = rsqrtf(tot / (float)DM + 1e-5f);
    bf16x2 o;
    o[0] = (__bf16)(v.x * rinv * w[2 * t]);
    o[1] = (__bf16)(v.y * rinv * w[2 * t + 1]);
    *(bf16x2*)&out[(size_t)row * DM + 2 * t] = o;
}

// ---------------------------------------------------------------------------
// bf16 MFMA GEMM, global_load_lds staging, source-preswizzled LDS.
// out[M,N] = A[M,K] @ BT[N,K]^T (+bias) (+res). BN=128, BK=32, 4 waves 2x2.
// ---------------------------------------------------------------------------
template<int BM, int EPI>
__global__ __launch_bounds__(256)
void gemm_bf16(const __bf16* __restrict__ A, const __bf16* __restrict__ BT,
               const float* __restrict__ bias, const float* __restrict__ res,
               void* __restrict__ out, int M, int N, int K) {
    __shared__ __align__(16) char AsB[BM * 64];
    __shared__ __align__(16) char BsB[128 * 64];
    const int t = threadIdx.x;
    const int w = t >> 6, l = t & 63, c = l & 15, g = l >> 4;
    const int wr = w >> 1, wc = w & 1;
    const int bm = blockIdx.y * BM, bn = blockIdx.x * 128;
    constexpr int HM = BM / 2, WM = BM / 32;
    f32x4 acc[WM][4];
#pragma unroll
    for (int m = 0; m < WM; ++m)
#pragma unroll
        for (int n = 0; n < 4; ++n) acc[m][n] = (f32x4){0.f, 0.f, 0.f, 0.f};
    // staging: dest byte = t*16 -> row t>>2, group t&3. source k-group preswizzled.
    const int srow = t >> 2;
    const int kcol = ((t & 3) ^ ((t >> 3) & 3)) << 3;
    const __bf16* Ap = A + (size_t)(bm + srow) * K + kcol;
    const __bf16* Bp = BT + (size_t)(bn + srow) * K + kcol;
    char* dA = AsB + t * 16;
    char* dB = BsB + t * 16;
    char* dB2 = BsB + 4096 + t * 16;
    const int sw = (g ^ ((c >> 1) & 3)) << 4;  // read-side swizzled group byte
    for (int k0 = 0; k0 < K; k0 += 32) {
        gl_lds16(Ap + k0, dA);
        if constexpr (BM == 128) gl_lds16(Ap + (size_t)64 * K + k0, AsB + 4096 + t * 16);
        gl_lds16(Bp + k0, dB);
        gl_lds16(Bp + (size_t)64 * K + k0, dB2);
        __syncthreads();
        bf16x8 af[WM], bf_[4];
#pragma unroll
        for (int m = 0; m < WM; ++m)
            af[m] = *(const bf16x8*)(AsB + (wr * HM + m * 16 + c) * 64 + sw);
#pragma unroll
        for (int n = 0; n < 4; ++n)
            bf_[n] = *(const bf16x8*)(BsB + (wc * 64 + n * 16 + c) * 64 + sw);
#pragma unroll
        for (int m = 0; m < WM; ++m)
#pragma unroll
            for (int n = 0; n < 4; ++n)
                acc[m][n] = __builtin_amdgcn_mfma_f32_16x16x32_bf16(af[m], bf_[n], acc[m][n], 0, 0, 0);
        __syncthreads();
    }
#pragma unroll
    for (int m = 0; m < WM; ++m)
#pragma unroll
        for (int n = 0; n < 4; ++n) {
            int rowb = bm + wr * HM + m * 16 + 4 * g;
            int col = bn + wc * 64 + n * 16 + c;
            float bv = bias ? bias[col] : 0.f;
#pragma unroll
            for (int r = 0; r < 4; ++r) {
                size_t idx = (size_t)(rowb + r) * N + col;
                float val = acc[m][n][r] + bv;
                if constexpr (EPI == 0) {
                    ((__bf16*)out)[idx] = (__bf16)val;
                } else {
                    if (res) val += res[idx];
                    ((float*)out)[idx] = val;
                }
            }
        }
}

// ---------------------------------------------------------------------------
// SwiGLU GEMM: mid = silu(A@GT^T) * (A@UT^T), bf16 out. BM=128.
// ---------------------------------------------------------------------------
__global__ __launch_bounds__(256)
void gemm_swiglu(const __bf16* __restrict__ A, const __bf16* __restrict__ GT,
                 const __bf16* __restrict__ UT, __bf16* __restrict__ out,
                 int M, int N, int K) {
    __shared__ __align__(16) char AsB[128 * 64];
    __shared__ __align__(16) char GsB[128 * 64];
    __shared__ __align__(16) char UsB[128 * 64];
    const int t = threadIdx.x;
    const int w = t >> 6, l = t & 63, c = l & 15, g = l >> 4;
    const int wr = w >> 1, wc = w & 1;
    const int bm = blockIdx.y * 128, bn = blockIdx.x * 128;
    f32x4 accg[4][4], accu[4][4];
#pragma unroll
    for (int m = 0; m < 4; ++m)
#pragma unroll
        for (int n = 0; n < 4; ++n) {
            accg[m][n] = (f32x4){0.f, 0.f, 0.f, 0.f};
            accu[m][n] = (f32x4){0.f, 0.f, 0.f, 0.f};
        }
    const int srow = t >> 2;
    const int kcol = ((t & 3) ^ ((t >> 3) & 3)) << 3;
    const __bf16* Ap = A + (size_t)(bm + srow) * K + kcol;
    const __bf16* Gp = GT + (size_t)(bn + srow) * K + kcol;
    const __bf16* Up = UT + (size_t)(bn + srow) * K + kcol;
    const int sw = (g ^ ((c >> 1) & 3)) << 4;
    for (int k0 = 0; k0 < K; k0 += 32) {
        gl_lds16(Ap + k0, AsB + t * 16);
        gl_lds16(Ap + (size_t)64 * K + k0, AsB + 4096 + t * 16);
        gl_lds16(Gp + k0, GsB + t * 16);
        gl_lds16(Gp + (size_t)64 * K + k0, GsB + 4096 + t * 16);
        gl_lds16(Up + k0, UsB + t * 16);
        gl_lds16(Up + (size_t)64 * K + k0, UsB + 4096 + t * 16);
        __syncthreads();
        bf16x8 af[4], gf[4], uf[4];
#pragma unroll
        for (int m = 0; m < 4; ++m)
            af[m] = *(const bf16x8*)(AsB + (wr * 64 + m * 16 + c) * 64 + sw);
#pragma unroll
        for (int n = 0; n < 4; ++n) {
            gf[n] = *(const bf16x8*)(GsB + (wc * 64 + n * 16 + c) * 64 + sw);
            uf[n] = *(const bf16x8*)(UsB + (wc * 64 + n * 16 + c) * 64 + sw);
        }
#pragma unroll
        for (int m = 0; m < 4; ++m)
#pragma unroll
            for (int n = 0; n < 4; ++n) {
                accg[m][n] = __builtin_amdgcn_mfma_f32_16x16x32_bf16(af[m], gf[n], accg[m][n], 0, 0, 0);
                accu[m][n] = __builtin_amdgcn_mfma_f32_16x16x32_bf16(af[m], uf[n], accu[m][n], 0, 0, 0);
            }
        __syncthreads();
    }
#pragma unroll
    for (int m = 0; m < 4; ++m)
#pragma unroll
        for (int n = 0; n < 4; ++n) {
            int rowb = bm + wr * 64 + m * 16 + 4 * g;
            int col = bn + wc * 64 + n * 16 + c;
#pragma unroll
            for (int r = 0; r < 4; ++r) {
                float gv = accg[m][n][r];
                float uv = accu[m][n][r];
                float sg = gv / (1.f + __expf(-gv));
                out[(size_t)(rowb + r) * N + col] = (__bf16)(sg * uv);
            }
        }
}

// ---------------------------------------------------------------------------
// neighbor affinity log a (from merged aqk buffer, row stride 1024)
// ---------------------------------------------------------------------------
__global__ __launch_bounds__(256)
void affinity_dots(const __bf16* __restrict__ aqk, float* __restrict__ la) {
    int i = blockIdx.x * 256 + threadIdx.x;
    int b = blockIdx.y;
    if (i >= Sn - 1) { la[b * Sn + i] = 0.f; return; }
    const __bf16* Qi = aqk + (size_t)(b * Sn + i) * 1024;
    const __bf16* Ki = Qi + 512;
    float sf = 0.f, sb = 0.f;
#pragma unroll 4
    for (int d = 0; d < DM / 8; ++d) {
        bf16x8 q0 = *(const bf16x8*)(Qi + d * 8);
        bf16x8 q1 = *(const bf16x8*)(Qi + 1024 + d * 8);
        bf16x8 k0 = *(const bf16x8*)(Ki + d * 8);
        bf16x8 k1 = *(const bf16x8*)(Ki + 1024 + d * 8);
#pragma unroll
        for (int j = 0; j < 8; ++j) {
            sf += (float)q0[j] * (float)k1[j];
            sb += (float)q1[j] * (float)k0[j];
        }
    }
    sf *= (1.f / 512.f);
    sb *= (1.f / 512.f);
    float a = 0.5f * (1.f / (1.f + __expf(-sf)) + 1.f / (1.f + __expf(-sb)));
    la[b * Sn + i] = __logf(a);
}

// inclusive-scan of log-a -> L. one block (256 thr) per batch.
__global__ __launch_bounds__(256)
void scan_kernel(const float* __restrict__ la, float* __restrict__ L) {
    int b = blockIdx.x, j = threadIdx.x;
    __shared__ float sc[256];
    float4 v = *(const float4*)&la[b * Sn + 4 * j];
    float s0 = v.x, s1 = s0 + v.y, s2 = s1 + v.z, s3 = s2 + v.w;
    sc[j] = s3;
    __syncthreads();
    for (int off = 1; off < 256; off <<= 1) {
        float add = (j >= off) ? sc[j - off] : 0.f;
        __syncthreads();
        sc[j] += add;
        __syncthreads();
    }
    float base = sc[j] - s3;
    if (j == 0) L[b * Sn] = 0.f;
    L[b * Sn + 4 * j + 1] = base + s0;
    L[b * Sn + 4 * j + 2] = base + s1;
    L[b * Sn + 4 * j + 3] = base + s2;
    if (4 * j + 4 < Sn) L[b * Sn + 4 * j + 4] = base + s3;
}

// ---------------------------------------------------------------------------
// Flash-style differential attention. XOR-swizzled LDS, gl_lds K staging,
// XCD-locality block swizzle, C hoisted, setprio around MFMA.
// ---------------------------------------------------------------------------
__global__ __launch_bounds__(256)
void attn_mfma(const __bf16* __restrict__ qkv, const float* __restrict__ L,
               const int* __restrict__ mask, const float* __restrict__ lam_p,
               float* __restrict__ ctx) {
    // linear grid 512; keep all 16 q-blocks of one (b,h) on one XCD
    int x = blockIdx.x;
    int xcd = x & 7, idx = x >> 3;
    int bh = xcd * 4 + (idx >> 4);   // 0..31
    int qb = idx & 15;
    int b = bh >> 3, h = bh & 7;
    const int t = threadIdx.x;
    const int w = t >> 6, l = t & 63, c = l & 15, g = l >> 4;

    __shared__ __align__(16) char KldsB[64 * 256];      // [k][16 grp]: grp 0-7 mat0, 8-15 mat1; swz ^(k&7)
    __shared__ __align__(16) char VtB[64 * 128];        // [d][8 grp of k], swz ^(d&7)
    __shared__ __align__(16) char PldsB[2][64 * 128];   // [q][8 grp of k], swz ^(q&7)
    __shared__ float Lk_s[64];
    __shared__ float msk_s[64];
    __shared__ float fs_s[2][64];
    __shared__ float ls_s[2][64];

    const int q0 = qb * 64;
    const int qg = q0 + 16 * w + c;
    float Lq = L[b * Sn + qg];
    float lam = lam_p[0];
    bf16x8 qf[2][2];
#pragma unroll
    for (int mat = 0; mat < 2; ++mat)
#pragma unroll
        for (int dh = 0; dh < 2; ++dh)
            qf[mat][dh] = *(const bf16x8*)(qkv + (size_t)(b * Sn + qg) * QKVN + mat * 512 + h * 64 + dh * 32 + g * 8);
    f32x4 O[2][4];
#pragma unroll
    for (int mat = 0; mat < 2; ++mat)
#pragma unroll
        for (int nd = 0; nd < 4; ++nd) O[mat][nd] = (f32x4){0.f, 0.f, 0.f, 0.f};
    float m_run[2] = {-INFINITY, -INFINITY};
    float l_run[2] = {0.f, 0.f};
    const int cs = c & 7;  // read-side swizzle key (row&7 == c&7 for 16-strided rows)

    for (int kt = 0; kt < 16; ++kt) {
        const size_t kbase = (size_t)(b * Sn + kt * 64);
        // ---- K via global_load_lds, source preswizzled ----
#pragma unroll
        for (int rep = 0; rep < 4; ++rep) {
            int krow = rep * 16 + (t >> 4);
            int mat = (t >> 3) & 1;
            int lg = (t & 7) ^ (krow & 7);
            gl_lds16(qkv + (kbase + krow) * QKVN + 1024 + mat * 512 + h * 64 + lg * 8,
                     KldsB + rep * 4096 + t * 16);
        }
        // ---- V -> Vt (transposed, swizzled writes) ----
#pragma unroll
        for (int rep = 0; rep < 2; ++rep) {
            int k = l;
            int dg = rep * 4 + w;  // 0..7
            bf16x8 val = *(const bf16x8*)(qkv + (kbase + k) * QKVN + 2048 + h * 64 + dg * 8);
#pragma unroll
            for (int j = 0; j < 8; ++j)
                *(__bf16*)(VtB + (dg * 8 + j) * 128 + ((((k >> 3) ^ j) << 4) | ((k & 7) << 1))) = val[j];
        }
        if (t < 64) {
            Lk_s[t] = L[b * Sn + kt * 64 + t];
            msk_s[t] = (float)mask[b * Sn + kt * 64 + t];
        }
        __syncthreads();
        // ---- hoisted per-k C and mask ----
        float Cv[16], msel[16];
#pragma unroll
        for (int kf = 0; kf < 4; ++kf)
#pragma unroll
            for (int r = 0; r < 4; ++r) {
                int kk = kf * 16 + 4 * g + r;
                Cv[kf * 4 + r] = __expf(-fabsf(Lq - Lk_s[kk]));
                msel[kf * 4 + r] = msk_s[kk];
            }
        // ---- QK^T (swapped), online softmax, P = C*e ----
#pragma unroll
        for (int mat = 0; mat < 2; ++mat) {
            f32x4 s[4];
            __builtin_amdgcn_s_setprio(1);
#pragma unroll
            for (int kf = 0; kf < 4; ++kf) {
                f32x4 a = (f32x4){0.f, 0.f, 0.f, 0.f};
#pragma unroll
                for (int dh = 0; dh < 2; ++dh) {
                    bf16x8 kfr = *(const bf16x8*)(KldsB + (kf * 16 + c) * 256 + (mat * 8 + ((dh * 4 + g) ^ cs)) * 16);
                    a = __builtin_amdgcn_mfma_f32_16x16x32_bf16(kfr, qf[mat][dh], a, 0, 0, 0);
                }
                s[kf] = a;
            }
            __builtin_amdgcn_s_setprio(0);
            float tm = -INFINITY;
#pragma unroll
            for (int kf = 0; kf < 4; ++kf)
#pragma unroll
                for (int r = 0; r < 4; ++r) {
                    float sv = (msel[kf * 4 + r] != 0.f) ? s[kf][r] * 0.125f : -1e9f;
                    s[kf][r] = sv;
                    tm = fmaxf(tm, sv);
                }
            tm = fmaxf(tm, __shfl_xor(tm, 16));
            tm = fmaxf(tm, __shfl_xor(tm, 32));
            float mn = fmaxf(m_run[mat], tm);
            float f = __expf(m_run[mat] - mn);
            m_run[mat] = mn;
            if (g == 0) fs_s[mat][16 * w + c] = f;
            float es = 0.f;
#pragma unroll
            for (int kf = 0; kf < 4; ++kf) {
                bf16x2 p01, p23;
                float e0 = __expf(s[kf][0] - mn);
                float e1 = __expf(s[kf][1] - mn);
                float e2 = __expf(s[kf][2] - mn);
                float e3 = __expf(s[kf][3] - mn);
                es += (e0 + e1) + (e2 + e3);
                p01[0] = (__bf16)(e0 * Cv[kf * 4 + 0]);
                p01[1] = (__bf16)(e1 * Cv[kf * 4 + 1]);
                p23[0] = (__bf16)(e2 * Cv[kf * 4 + 2]);
                p23[1] = (__bf16)(e3 * Cv[kf * 4 + 3]);
                // P row 16w+c, logical bytes kf*32+g*8 : grp = kf*2+(g>>1), off (g&1)*8
                char* pb = PldsB[mat] + (16 * w + c) * 128 + (((kf * 2 + (g >> 1)) ^ cs) << 4) + ((g & 1) << 3);
                *(bf16x2*)pb = p01;
                *(bf16x2*)(pb + 4) = p23;
            }
            es += __shfl_xor(es, 16);
            es += __shfl_xor(es, 32);
            l_run[mat] = l_run[mat] * f + es;
        }
        __syncthreads();
        // ---- PV: O = O*f + P.V ----
#pragma unroll
        for (int mat = 0; mat < 2; ++mat) {
            f32x4 fv = *(const f32x4*)&fs_s[mat][16 * w + 4 * g];
#pragma unroll
            for (int nd = 0; nd < 4; ++nd) O[mat][nd] *= fv;
            __builtin_amdgcn_s_setprio(1);
#pragma unroll
            for (int kh = 0; kh < 2; ++kh) {
                bf16x8 pa = *(const bf16x8*)(PldsB[mat] + (16 * w + c) * 128 + (((kh * 4 + g) ^ cs) << 4));
#pragma unroll
                for (int nd = 0; nd < 4; ++nd) {
                    bf16x8 vb = *(const bf16x8*)(VtB + (nd * 16 + c) * 128 + (((kh * 4 + g) ^ cs) << 4));
                    O[mat][nd] = __builtin_amdgcn_mfma_f32_16x16x32_bf16(pa, vb, O[mat][nd], 0, 0, 0);
                }
            }
            __builtin_amdgcn_s_setprio(0);
        }
        __syncthreads();
    }
    if (g == 0) {
        ls_s[0][16 * w + c] = l_run[0];
        ls_s[1][16 * w + c] = l_run[1];
    }
    __syncthreads();
    f32x4 l1 = *(const f32x4*)&ls_s[0][16 * w + 4 * g];
    f32x4 l2 = *(const f32x4*)&ls_s[1][16 * w + 4 * g];
#pragma unroll
    for (int nd = 0; nd < 4; ++nd)
#pragma unroll
        for (int r = 0; r < 4; ++r) {
            float val = O[0][nd][r] / l1[r] - lam * (O[1][nd][r] / l2[r]);
            int q = q0 + 16 * w + 4 * g + r;
            ctx[(size_t)(b * Sn + q) * DM + h * 64 + nd * 16 + c] = val;
        }
}

// ---------------------------------------------------------------------------
// GroupNorm split: stats (atomic partial sums) + apply
// ---------------------------------------------------------------------------
__global__ __launch_bounds__(256)
void gn_stats(const float* __restrict__ ctx, float* __restrict__ stats) {
    int b = blockIdx.x >> 3, h = blockIdx.x & 7;
    int s0 = blockIdx.y * 128;
    int t = threadIdx.x;
    float sum = 0.f, sq = 0.f;
    for (int i = t; i < 128 * 32; i += 256) {
        int s = s0 + (i >> 5), dp = (i & 31) * 2;
        float2 vv = *(const float2*)&ctx[(size_t)(b * Sn + s) * DM + h * 64 + dp];
        sum += vv.x + vv.y;
        sq += vv.x * vv.x + vv.y * vv.y;
    }
#pragma unroll
    for (int off = 32; off; off >>= 1) {
        sum += __shfl_xor(sum, off);
        sq += __shfl_xor(sq, off);
    }
    __shared__ float rs[4], rq[4];
    int wid = t >> 6;
    if ((t & 63) == 0) { rs[wid] = sum; rq[wid] = sq; }
    __syncthreads();
    if (t == 0) {
        atomicAdd(&stats[blockIdx.x * 2], rs[0] + rs[1] + rs[2] + rs[3]);
        atomicAdd(&stats[blockIdx.x * 2 + 1], rq[0] + rq[1] + rq[2] + rq[3]);
    }
}

__global__ __launch_bounds__(256)
void gn_apply(const float* __restrict__ ctx, const float* __restrict__ stats,
              const float* __restrict__ gamma, const float* __restrict__ beta,
              __bf16* __restrict__ out) {
    int row = blockIdx.x;               // b*Sn + s
    int b = row >> 10;
    int t = threadIdx.x;
    int dpair = t * 2;                  // 0..511
    int h = dpair >> 6;
    float mean = stats[(b * 8 + h) * 2] * (1.f / 65536.f);
    float msq = stats[(b * 8 + h) * 2 + 1] * (1.f / 65536.f);
    float rinv = rsqrtf(msq - mean * mean + 1e-5f);
    size_t off_ = (size_t)row * DM + dpair;
    float2 vv = *(const float2*)&ctx[off_];
    bf16x2 o;
    o[0] = (__bf16)(((vv.x - mean) * rinv * gamma[dpair] + beta[dpair]) * 0.8f);
    o[1] = (__bf16)(((vv.y - mean) * rinv * gamma[dpair + 1] + beta[dpair + 1]) * 0.8f);
    *(bf16x2*)&out[off_] = o;
}

// ---------------------------------------------------------------------------
extern "C" void kernel_launch(void* const* d_in, const int* in_sizes, int n_in,
                              void* d_out, int out_size, void* d_ws, size_t ws_size,
                              hipStream_t stream) {
    const float* x        = (const float*)d_in[0];
    const int*   mask     = (const int*)d_in[1];
    const float* lam      = (const float*)d_in[2];
    const float* wq_w     = (const float*)d_in[3];
    const float* wq_b     = (const float*)d_in[4];
    const float* wk_w     = (const float*)d_in[5];
    const float* wk_b     = (const float*)d_in[6];
    const float* wv_w     = (const float*)d_in[7];
    const float* wv_b     = (const float*)d_in[8];
    const float* out_w    = (const float*)d_in[9];
    const float* out_b    = (const float*)d_in[10];
    const float* gn_gamma = (const float*)d_in[11];
    const float* gn_beta  = (const float*)d_in[12];
    const float* aq_w     = (const float*)d_in[13];
    const float* aq_b     = (const float*)d_in[14];
    const float* ak_w     = (const float*)d_in[15];
    const float* ak_b     = (const float*)d_in[16];
    const float* wg_w     = (const float*)d_in[17];
    const float* w1_w     = (const float*)d_in[18];
    const float* w2_w     = (const float*)d_in[19];
    const float* norm1_w  = (const float*)d_in[20];
    const float* norm2_w  = (const float*)d_in[21];

    char* ws = (char*)d_ws;
    __bf16* aqkT = (__bf16*)(ws + 0);            // [1024][512]  1MB
    __bf16* qkvT = (__bf16*)(ws + 1 * MB);       // [2560][512]  2.5MB
    __bf16* outT = (__bf16*)(ws + 7 * MB / 2);   // [512][512]   0.5MB
    __bf16* wgT  = (__bf16*)(ws + 4 * MB);       // [2048][512]  2MB
    __bf16* w1T  = (__bf16*)(ws + 6 * MB);       // 2MB
    __bf16* w2T  = (__bf16*)(ws + 8 * MB);       // [512][2048]  2MB
    __bf16* xn   = (__bf16*)(ws + 10 * MB);      // [4096][512]  4MB
    __bf16* aqk  = (__bf16*)(ws + 14 * MB);      // [4096][1024] 8MB
    __bf16* qkv  = (__bf16*)(ws + 22 * MB);      // [4096][2560] 20MB
    float*  la   = (float*)(ws + 42 * MB);
    float*  Lb   = (float*)(ws + 42 * MB + 64 * 1024);
    float*  stats= (float*)(ws + 42 * MB + 128 * 1024);   // 64 floats
    float*  aqk_b= (float*)(ws + 42 * MB + 192 * 1024);
    float*  qkv_b= (float*)(ws + 42 * MB + 256 * 1024);
    float*  ctx  = (float*)(ws + 43 * MB);       // 8MB
    __bf16* ctxb = (__bf16*)(ws + 51 * MB);      // 4MB
    float*  h    = (float*)(ws + 55 * MB);       // 8MB
    __bf16* hn   = (__bf16*)(ws + 14 * MB);      // reuse aqk
    __bf16* mid  = (__bf16*)(ws + 22 * MB);      // reuse qkv
    float*  outp = (float*)d_out;

    const int M = Bn * Sn;  // 4096
    dim3 thr(32, 8);

    hipMemsetAsync(stats, 0, 64 * sizeof(float), stream);

    TransBatch ta = {{aq_w, ak_w, wv_w, out_w},
                     {aqkT, aqkT + 512 * 512, qkvT + (size_t)2048 * 512, outT}};
    transpose_kernel<<<dim3(16, 16, 4), thr, 0, stream>>>(ta, 512, 512);
    TransBatch tbq = {{wq_w, wk_w, nullptr, nullptr},
                      {qkvT, qkvT + (size_t)1024 * 512, nullptr, nullptr}};
    transpose_kernel<<<dim3(32, 16, 2), thr, 0, stream>>>(tbq, 512, 1024);
    TransBatch tc = {{wg_w, w1_w, nullptr, nullptr}, {wgT, w1T, nullptr, nullptr}};
    transpose_kernel<<<dim3(64, 16, 2), thr, 0, stream>>>(tc, 512, 2048);
    TransBatch td = {{w2_w, nullptr, nullptr, nullptr}, {w2T, nullptr, nullptr, nullptr}};
    transpose_kernel<<<dim3(16, 64, 1), thr, 0, stream>>>(td, 2048, 512);

    pack_biases<<<14, 256, 0, stream>>>(aq_b, ak_b, wq_b, wk_b, wv_b, aqk_b, qkv_b);

    rmsnorm_kernel<<<M, 256, 0, stream>>>(x, norm1_w, xn);

    gemm_bf16<64, 0><<<dim3(8, 64), 256, 0, stream>>>(xn, aqkT, aqk_b, nullptr, aqk, M, 1024, 512);
    affinity_dots<<<dim3(4, 4), 256, 0, stream>>>(aqk, la);
    scan_kernel<<<Bn, 256, 0, stream>>>(la, Lb);

    gemm_bf16<128, 0><<<dim3(20, 32), 256, 0, stream>>>(xn, qkvT, qkv_b, nullptr, qkv, M, QKVN, 512);

    attn_mfma<<<512, 256, 0, stream>>>(qkv, Lb, mask, lam, ctx);

    gn_stats<<<dim3(32, 8), 256, 0, stream>>>(ctx, stats);
    gn_apply<<<M, 256, 0, stream>>>(ctx, stats, gn_gamma, gn_beta, ctxb);

    gemm_bf16<64, 1><<<dim3(4, 64), 256, 0, stream>>>(ctxb, outT, out_b, x, h, M, 512, 512);

    rmsnorm_kernel<<<M, 256, 0, stream>>>(h, norm2_w, hn);

    gemm_swiglu<<<dim3(16, 32), 256, 0, stream>>>(hn, wgT, w1T, mid, M, DFF, 512);

    gemm_bf16<64, 1><<<dim3(4, 64), 256, 0, stream>>>(mid, w2T, nullptr, h, outp, M, 512, DFF);
}

// Round 6
// 352.114 us; speedup vs baseline: 6.5500x; 1.0398x over previous
//
#include <hip/hip_runtime.h>
#include <math.h>

#define Bn 4
#define Sn 1024
#define DM 512
#define NH 8
#define DFF 2048
#define QKVN 2560

typedef __attribute__((ext_vector_type(8))) __bf16 bf16x8;
typedef __attribute__((ext_vector_type(2))) __bf16 bf16x2;
typedef __attribute__((ext_vector_type(4))) float f32x4;

#define MB (1u<<20)

// async global->LDS, 16B per lane. dest = wave-uniform base + lane*16.
__device__ __forceinline__ void gl_lds16(const void* g, void* l) {
    __builtin_amdgcn_global_load_lds(
        (const __attribute__((address_space(1))) void*)g,
        (__attribute__((address_space(3))) void*)l, 16, 0, 0);
}

// ---------------------------------------------------------------------------
// batched transpose + f32->bf16: dst[n][k] = src[k][n]
// ---------------------------------------------------------------------------
struct TransBatch { const float* src[4]; __bf16* dst[4]; };

__global__ __launch_bounds__(256)
void transpose_kernel(TransBatch tb, int K, int N) {
    const float* w = tb.src[blockIdx.z];
    __bf16* wT = tb.dst[blockIdx.z];
    __shared__ float tile[32][33];
    int n0 = blockIdx.x * 32, k0 = blockIdx.y * 32;
    int tx = threadIdx.x, ty = threadIdx.y;  // 32 x 8
#pragma unroll
    for (int i = 0; i < 4; ++i)
        tile[ty + 8 * i][tx] = w[(size_t)(k0 + ty + 8 * i) * N + n0 + tx];
    __syncthreads();
#pragma unroll
    for (int i = 0; i < 4; ++i)
        wT[(size_t)(n0 + ty + 8 * i) * K + k0 + tx] = (__bf16)tile[tx][ty + 8 * i];
}

// pack biases: aqk_b[1024] = aq_b|ak_b ; qkv_b[2560] = wq_b|wk_b|wv_b
__global__ __launch_bounds__(256)
void pack_biases(const float* aq_b, const float* ak_b, const float* wq_b,
                 const float* wk_b, const float* wv_b,
                 float* aqk_b, float* qkv_b) {
    int t = blockIdx.x * 256 + threadIdx.x;
    if (t < 512) aqk_b[t] = aq_b[t];
    else if (t < 1024) aqk_b[t] = ak_b[t - 512];
    else if (t < 2048) qkv_b[t - 1024] = wq_b[t - 1024];
    else if (t < 3072) qkv_b[1024 + t - 2048] = wk_b[t - 2048];
    else if (t < 3584) qkv_b[2048 + t - 3072] = wv_b[t - 3072];
}

// ---------------------------------------------------------------------------
// RMSNorm: f32 in -> bf16 out. one block per row.
// ---------------------------------------------------------------------------
__global__ __launch_bounds__(256)
void rmsnorm_kernel(const float* __restrict__ x, const float* __restrict__ w,
                    __bf16* __restrict__ out) {
    int row = blockIdx.x;
    const float* xr = x + (size_t)row * DM;
    int t = threadIdx.x;
    float2 v = *(const float2*)&xr[2 * t];
    float ss = v.x * v.x + v.y * v.y;
#pragma unroll
    for (int off = 32; off; off >>= 1) ss += __shfl_xor(ss, off);
    __shared__ float red[4];
    int wid = t >> 6;
    if ((t & 63) == 0) red[wid] = ss;
    __syncthreads();
    float tot = red[0] + red[1] + red[2] + red[3];
    float rinv = rsqrtf(tot / (float)DM + 1e-5f);
    bf16x2 o;
    o[0] = (__bf16)(v.x * rinv * w[2 * t]);
    o[1] = (__bf16)(v.y * rinv * w[2 * t + 1]);
    *(bf16x2*)&out[(size_t)row * DM + 2 * t] = o;
}

// ---------------------------------------------------------------------------
// bf16 MFMA GEMM, global_load_lds staging, source-preswizzled LDS.
// out[M,N] = A[M,K] @ BT[N,K]^T (+bias) (+res). BK=32, 4 waves 2x2.
// ---------------------------------------------------------------------------
template<int BM, int BN, int EPI>
__global__ __launch_bounds__(256)
void gemm_bf16(const __bf16* __restrict__ A, const __bf16* __restrict__ BT,
               const float* __restrict__ bias, const float* __restrict__ res,
               void* __restrict__ out, int M, int N, int K) {
    __shared__ __align__(16) char AsB[BM * 64];
    __shared__ __align__(16) char BsB[BN * 64];
    const int t = threadIdx.x;
    const int w = t >> 6, l = t & 63, c = l & 15, g = l >> 4;
    const int wr = w >> 1, wc = w & 1;
    const int bm = blockIdx.y * BM, bn = blockIdx.x * BN;
    constexpr int HM = BM / 2, WM = BM / 32, HN = BN / 2, WN = BN / 32;
    f32x4 acc[WM][WN];
#pragma unroll
    for (int m = 0; m < WM; ++m)
#pragma unroll
        for (int n = 0; n < WN; ++n) acc[m][n] = (f32x4){0.f, 0.f, 0.f, 0.f};
    const int srow = t >> 2;
    const int kcol = ((t & 3) ^ ((t >> 3) & 3)) << 3;
    const __bf16* Ap = A + (size_t)(bm + srow) * K + kcol;
    const __bf16* Bp = BT + (size_t)(bn + srow) * K + kcol;
    const int sw = (g ^ ((c >> 1) & 3)) << 4;  // read-side swizzled group byte
    for (int k0 = 0; k0 < K; k0 += 32) {
        gl_lds16(Ap + k0, AsB + t * 16);
        if constexpr (BM == 128) gl_lds16(Ap + (size_t)64 * K + k0, AsB + 4096 + t * 16);
        gl_lds16(Bp + k0, BsB + t * 16);
        if constexpr (BN == 128) gl_lds16(Bp + (size_t)64 * K + k0, BsB + 4096 + t * 16);
        __syncthreads();
        bf16x8 af[WM], bf_[WN];
#pragma unroll
        for (int m = 0; m < WM; ++m)
            af[m] = *(const bf16x8*)(AsB + (wr * HM + m * 16 + c) * 64 + sw);
#pragma unroll
        for (int n = 0; n < WN; ++n)
            bf_[n] = *(const bf16x8*)(BsB + (wc * HN + n * 16 + c) * 64 + sw);
#pragma unroll
        for (int m = 0; m < WM; ++m)
#pragma unroll
            for (int n = 0; n < WN; ++n)
                acc[m][n] = __builtin_amdgcn_mfma_f32_16x16x32_bf16(af[m], bf_[n], acc[m][n], 0, 0, 0);
        __syncthreads();
    }
#pragma unroll
    for (int m = 0; m < WM; ++m)
#pragma unroll
        for (int n = 0; n < WN; ++n) {
            int rowb = bm + wr * HM + m * 16 + 4 * g;
            int col = bn + wc * HN + n * 16 + c;
            float bv = bias ? bias[col] : 0.f;
#pragma unroll
            for (int r = 0; r < 4; ++r) {
                size_t idx = (size_t)(rowb + r) * N + col;
                float val = acc[m][n][r] + bv;
                if constexpr (EPI == 0) {
                    ((__bf16*)out)[idx] = (__bf16)val;
                } else {
                    if (res) val += res[idx];
                    ((float*)out)[idx] = val;
                }
            }
        }
}

// ---------------------------------------------------------------------------
// SwiGLU GEMM: mid = silu(A@GT^T) * (A@UT^T), bf16 out. 128x128.
// ---------------------------------------------------------------------------
__global__ __launch_bounds__(256)
void gemm_swiglu(const __bf16* __restrict__ A, const __bf16* __restrict__ GT,
                 const __bf16* __restrict__ UT, __bf16* __restrict__ out,
                 int M, int N, int K) {
    __shared__ __align__(16) char AsB[128 * 64];
    __shared__ __align__(16) char GsB[128 * 64];
    __shared__ __align__(16) char UsB[128 * 64];
    const int t = threadIdx.x;
    const int w = t >> 6, l = t & 63, c = l & 15, g = l >> 4;
    const int wr = w >> 1, wc = w & 1;
    const int bm = blockIdx.y * 128, bn = blockIdx.x * 128;
    f32x4 accg[4][4], accu[4][4];
#pragma unroll
    for (int m = 0; m < 4; ++m)
#pragma unroll
        for (int n = 0; n < 4; ++n) {
            accg[m][n] = (f32x4){0.f, 0.f, 0.f, 0.f};
            accu[m][n] = (f32x4){0.f, 0.f, 0.f, 0.f};
        }
    const int srow = t >> 2;
    const int kcol = ((t & 3) ^ ((t >> 3) & 3)) << 3;
    const __bf16* Ap = A + (size_t)(bm + srow) * K + kcol;
    const __bf16* Gp = GT + (size_t)(bn + srow) * K + kcol;
    const __bf16* Up = UT + (size_t)(bn + srow) * K + kcol;
    const int sw = (g ^ ((c >> 1) & 3)) << 4;
    for (int k0 = 0; k0 < K; k0 += 32) {
        gl_lds16(Ap + k0, AsB + t * 16);
        gl_lds16(Ap + (size_t)64 * K + k0, AsB + 4096 + t * 16);
        gl_lds16(Gp + k0, GsB + t * 16);
        gl_lds16(Gp + (size_t)64 * K + k0, GsB + 4096 + t * 16);
        gl_lds16(Up + k0, UsB + t * 16);
        gl_lds16(Up + (size_t)64 * K + k0, UsB + 4096 + t * 16);
        __syncthreads();
        bf16x8 af[4], gf[4], uf[4];
#pragma unroll
        for (int m = 0; m < 4; ++m)
            af[m] = *(const bf16x8*)(AsB + (wr * 64 + m * 16 + c) * 64 + sw);
#pragma unroll
        for (int n = 0; n < 4; ++n) {
            gf[n] = *(const bf16x8*)(GsB + (wc * 64 + n * 16 + c) * 64 + sw);
            uf[n] = *(const bf16x8*)(UsB + (wc * 64 + n * 16 + c) * 64 + sw);
        }
#pragma unroll
        for (int m = 0; m < 4; ++m)
#pragma unroll
            for (int n = 0; n < 4; ++n) {
                accg[m][n] = __builtin_amdgcn_mfma_f32_16x16x32_bf16(af[m], gf[n], accg[m][n], 0, 0, 0);
                accu[m][n] = __builtin_amdgcn_mfma_f32_16x16x32_bf16(af[m], uf[n], accu[m][n], 0, 0, 0);
            }
        __syncthreads();
    }
#pragma unroll
    for (int m = 0; m < 4; ++m)
#pragma unroll
        for (int n = 0; n < 4; ++n) {
            int rowb = bm + wr * 64 + m * 16 + 4 * g;
            int col = bn + wc * 64 + n * 16 + c;
#pragma unroll
            for (int r = 0; r < 4; ++r) {
                float gv = accg[m][n][r];
                float uv = accu[m][n][r];
                float sg = gv / (1.f + __expf(-gv));
                out[(size_t)(rowb + r) * N + col] = (__bf16)(sg * uv);
            }
        }
}

// ---------------------------------------------------------------------------
// neighbor affinity log a (from merged aqk buffer, row stride 1024)
// ---------------------------------------------------------------------------
__global__ __launch_bounds__(256)
void affinity_dots(const __bf16* __restrict__ aqk, float* __restrict__ la) {
    int i = blockIdx.x * 256 + threadIdx.x;
    int b = blockIdx.y;
    if (i >= Sn - 1) { la[b * Sn + i] = 0.f; return; }
    const __bf16* Qi = aqk + (size_t)(b * Sn + i) * 1024;
    const __bf16* Ki = Qi + 512;
    float sf = 0.f, sb = 0.f;
#pragma unroll 4
    for (int d = 0; d < DM / 8; ++d) {
        bf16x8 q0 = *(const bf16x8*)(Qi + d * 8);
        bf16x8 q1 = *(const bf16x8*)(Qi + 1024 + d * 8);
        bf16x8 k0 = *(const bf16x8*)(Ki + d * 8);
        bf16x8 k1 = *(const bf16x8*)(Ki + 1024 + d * 8);
#pragma unroll
        for (int j = 0; j < 8; ++j) {
            sf += (float)q0[j] * (float)k1[j];
            sb += (float)q1[j] * (float)k0[j];
        }
    }
    sf *= (1.f / 512.f);
    sb *= (1.f / 512.f);
    float a = 0.5f * (1.f / (1.f + __expf(-sf)) + 1.f / (1.f + __expf(-sb)));
    la[b * Sn + i] = __logf(a);
}

// inclusive-scan of log-a -> L. one block (256 thr) per batch.
__global__ __launch_bounds__(256)
void scan_kernel(const float* __restrict__ la, float* __restrict__ L) {
    int b = blockIdx.x, j = threadIdx.x;
    __shared__ float sc[256];
    float4 v = *(const float4*)&la[b * Sn + 4 * j];
    float s0 = v.x, s1 = s0 + v.y, s2 = s1 + v.z, s3 = s2 + v.w;
    sc[j] = s3;
    __syncthreads();
    for (int off = 1; off < 256; off <<= 1) {
        float add = (j >= off) ? sc[j - off] : 0.f;
        __syncthreads();
        sc[j] += add;
        __syncthreads();
    }
    float base = sc[j] - s3;
    if (j == 0) L[b * Sn] = 0.f;
    L[b * Sn + 4 * j + 1] = base + s0;
    L[b * Sn + 4 * j + 2] = base + s1;
    L[b * Sn + 4 * j + 3] = base + s2;
    if (4 * j + 4 < Sn) L[b * Sn + 4 * j + 4] = base + s3;
}

// ---------------------------------------------------------------------------
// Flash-style differential attention. 8 waves: waves 0-3 = mat0, 4-7 = mat1
// (same 64 q-rows). XOR-swizzled LDS, gl_lds K staging, XCD block swizzle.
// ---------------------------------------------------------------------------
__global__ __launch_bounds__(512)
void attn_mfma(const __bf16* __restrict__ qkv, const float* __restrict__ L,
               const int* __restrict__ mask, const float* __restrict__ lam_p,
               float* __restrict__ ctx) {
    // linear grid 512; keep all 16 q-blocks of one (b,h) on one XCD
    int x = blockIdx.x;
    int xcd = x & 7, idx = x >> 3;
    int bh = xcd * 4 + (idx >> 4);   // 0..31
    int qb = idx & 15;
    int b = bh >> 3, h = bh & 7;
    const int t = threadIdx.x;
    const int w = t >> 6, l = t & 63, c = l & 15, g = l >> 4;
    const int mat = w >> 2, ws = w & 3;

    __shared__ __align__(16) char KldsB[64 * 256];      // [k][16 grp]: 0-7 mat0, 8-15 mat1; swz ^(k&7)
    __shared__ __align__(16) char VtB[64 * 128];        // [d][8 grp of k], swz ^(d&7)
    __shared__ __align__(16) char PldsB[2][64 * 128];   // [q][8 grp of k], swz ^(q&7); reused f32 at end
    __shared__ float Lk_s[64];
    __shared__ float msk_s[64];
    __shared__ float fs_s[2][64];
    __shared__ float ls_s[2][64];

    const int q0 = qb * 64;
    const int qg = q0 + 16 * ws + c;
    float Lq = L[b * Sn + qg];
    float lam = lam_p[0];
    bf16x8 qf[2];
#pragma unroll
    for (int dh = 0; dh < 2; ++dh)
        qf[dh] = *(const bf16x8*)(qkv + (size_t)(b * Sn + qg) * QKVN + mat * 512 + h * 64 + dh * 32 + g * 8);
    f32x4 O[4];
#pragma unroll
    for (int nd = 0; nd < 4; ++nd) O[nd] = (f32x4){0.f, 0.f, 0.f, 0.f};
    float m_run = -INFINITY;
    float l_run = 0.f;
    const int cs = c & 7;  // read-side swizzle key

    for (int kt = 0; kt < 16; ++kt) {
        const size_t kbase = (size_t)(b * Sn + kt * 64);
        // ---- K via global_load_lds, source preswizzled (both mats) ----
#pragma unroll
        for (int rep = 0; rep < 2; ++rep) {
            int u = t & 255;
            int rr = (t >> 8) + 2 * rep;
            int krow = rr * 16 + (u >> 4);
            int km = (u >> 3) & 1;
            int lg = (u & 7) ^ (krow & 7);
            gl_lds16(qkv + (kbase + krow) * QKVN + 1024 + km * 512 + h * 64 + lg * 8,
                     KldsB + rr * 4096 + u * 16);
        }
        // ---- V -> Vt (transposed, swizzled writes), 1 rep @512 thr ----
        {
            int k = t & 63, dg = t >> 6;  // dg 0..7
            bf16x8 val = *(const bf16x8*)(qkv + (kbase + k) * QKVN + 2048 + h * 64 + dg * 8);
#pragma unroll
            for (int j = 0; j < 8; ++j)
                *(__bf16*)(VtB + (dg * 8 + j) * 128 + ((((k >> 3) ^ j) << 4) | ((k & 7) << 1))) = val[j];
        }
        if (t < 64) {
            Lk_s[t] = L[b * Sn + kt * 64 + t];
            msk_s[t] = (float)mask[b * Sn + kt * 64 + t];
        }
        __syncthreads();
        // ---- hoisted per-k C and mask bits ----
        float Cv[16];
        unsigned mbits = 0;
#pragma unroll
        for (int kf = 0; kf < 4; ++kf)
#pragma unroll
            for (int r = 0; r < 4; ++r) {
                int kk = kf * 16 + 4 * g + r;
                Cv[kf * 4 + r] = __expf(-fabsf(Lq - Lk_s[kk]));
                mbits |= (msk_s[kk] != 0.f ? 1u : 0u) << (kf * 4 + r);
            }
        // ---- QK^T (swapped) for own mat ----
        f32x4 s[4];
        __builtin_amdgcn_s_setprio(1);
#pragma unroll
        for (int kf = 0; kf < 4; ++kf) {
            f32x4 a = (f32x4){0.f, 0.f, 0.f, 0.f};
#pragma unroll
            for (int dh = 0; dh < 2; ++dh) {
                bf16x8 kfr = *(const bf16x8*)(KldsB + (kf * 16 + c) * 256 + (mat * 8 + ((dh * 4 + g) ^ cs)) * 16);
                a = __builtin_amdgcn_mfma_f32_16x16x32_bf16(kfr, qf[dh], a, 0, 0, 0);
            }
            s[kf] = a;
        }
        __builtin_amdgcn_s_setprio(0);
        // ---- online softmax ----
        float tm = -INFINITY;
#pragma unroll
        for (int kf = 0; kf < 4; ++kf)
#pragma unroll
            for (int r = 0; r < 4; ++r) {
                float sv = ((mbits >> (kf * 4 + r)) & 1u) ? s[kf][r] * 0.125f : -1e9f;
                s[kf][r] = sv;
                tm = fmaxf(tm, sv);
            }
        tm = fmaxf(tm, __shfl_xor(tm, 16));
        tm = fmaxf(tm, __shfl_xor(tm, 32));
        float mn = fmaxf(m_run, tm);
        float f = __expf(m_run - mn);
        m_run = mn;
        if (g == 0) fs_s[mat][16 * ws + c] = f;
        float es = 0.f;
#pragma unroll
        for (int kf = 0; kf < 4; ++kf) {
            bf16x2 p01, p23;
            float e0 = __expf(s[kf][0] - mn);
            float e1 = __expf(s[kf][1] - mn);
            float e2 = __expf(s[kf][2] - mn);
            float e3 = __expf(s[kf][3] - mn);
            es += (e0 + e1) + (e2 + e3);
            p01[0] = (__bf16)(e0 * Cv[kf * 4 + 0]);
            p01[1] = (__bf16)(e1 * Cv[kf * 4 + 1]);
            p23[0] = (__bf16)(e2 * Cv[kf * 4 + 2]);
            p23[1] = (__bf16)(e3 * Cv[kf * 4 + 3]);
            char* pb = PldsB[mat] + (16 * ws + c) * 128 + (((kf * 2 + (g >> 1)) ^ cs) << 4) + ((g & 1) << 3);
            *(bf16x2*)pb = p01;
            *(bf16x2*)(pb + 4) = p23;
        }
        es += __shfl_xor(es, 16);
        es += __shfl_xor(es, 32);
        l_run = l_run * f + es;
        __syncthreads();
        // ---- PV for own mat ----
        f32x4 fv = *(const f32x4*)&fs_s[mat][16 * ws + 4 * g];
#pragma unroll
        for (int nd = 0; nd < 4; ++nd) O[nd] *= fv;
        __builtin_amdgcn_s_setprio(1);
#pragma unroll
        for (int kh = 0; kh < 2; ++kh) {
            bf16x8 pa = *(const bf16x8*)(PldsB[mat] + (16 * ws + c) * 128 + (((kh * 4 + g) ^ cs) << 4));
#pragma unroll
            for (int nd = 0; nd < 4; ++nd) {
                bf16x8 vb = *(const bf16x8*)(VtB + (nd * 16 + c) * 128 + (((kh * 4 + g) ^ cs) << 4));
                O[nd] = __builtin_amdgcn_mfma_f32_16x16x32_bf16(pa, vb, O[nd], 0, 0, 0);
            }
        }
        __builtin_amdgcn_s_setprio(0);
        __syncthreads();
    }
    if (g == 0) ls_s[mat][16 * ws + c] = l_run;
    __syncthreads();
    f32x4 lv = *(const f32x4*)&ls_s[mat][16 * ws + 4 * g];
#pragma unroll
    for (int nd = 0; nd < 4; ++nd)
#pragma unroll
        for (int r = 0; r < 4; ++r) O[nd][r] /= lv[r];
    // mat1 publishes normalized O; mat0 combines and writes out
    float* Pf = (float*)PldsB;
    if (mat == 1) {
#pragma unroll
        for (int nd = 0; nd < 4; ++nd)
#pragma unroll
            for (int r = 0; r < 4; ++r)
                Pf[(16 * ws + 4 * g + r) * 64 + nd * 16 + c] = O[nd][r];
    }
    __syncthreads();
    if (mat == 0) {
#pragma unroll
        for (int nd = 0; nd < 4; ++nd)
#pragma unroll
            for (int r = 0; r < 4; ++r) {
                float val = O[nd][r] - lam * Pf[(16 * ws + 4 * g + r) * 64 + nd * 16 + c];
                int q = q0 + 16 * ws + 4 * g + r;
                ctx[(size_t)(b * Sn + q) * DM + h * 64 + nd * 16 + c] = val;
            }
    }
}

// ---------------------------------------------------------------------------
// GroupNorm split: stats (atomic partial sums) + apply
// ---------------------------------------------------------------------------
__global__ __launch_bounds__(256)
void gn_stats(const float* __restrict__ ctx, float* __restrict__ stats) {
    int b = blockIdx.x >> 3, h = blockIdx.x & 7;
    int s0 = blockIdx.y * 128;
    int t = threadIdx.x;
    float sum = 0.f, sq = 0.f;
    for (int i = t; i < 128 * 32; i += 256) {
        int s = s0 + (i >> 5), dp = (i & 31) * 2;
        float2 vv = *(const float2*)&ctx[(size_t)(b * Sn + s) * DM + h * 64 + dp];
        sum += vv.x + vv.y;
        sq += vv.x * vv.x + vv.y * vv.y;
    }
#pragma unroll
    for (int off = 32; off; off >>= 1) {
        sum += __shfl_xor(sum, off);
        sq += __shfl_xor(sq, off);
    }
    __shared__ float rs[4], rq[4];
    int wid = t >> 6;
    if ((t & 63) == 0) { rs[wid] = sum; rq[wid] = sq; }
    __syncthreads();
    if (t == 0) {
        atomicAdd(&stats[blockIdx.x * 2], rs[0] + rs[1] + rs[2] + rs[3]);
        atomicAdd(&stats[blockIdx.x * 2 + 1], rq[0] + rq[1] + rq[2] + rq[3]);
    }
}

__global__ __launch_bounds__(256)
void gn_apply(const float* __restrict__ ctx, const float* __restrict__ stats,
              const float* __restrict__ gamma, const float* __restrict__ beta,
              __bf16* __restrict__ out) {
    int row = blockIdx.x;               // b*Sn + s
    int b = row >> 10;
    int t = threadIdx.x;
    int dpair = t * 2;                  // 0..511
    int h = dpair >> 6;
    float mean = stats[(b * 8 + h) * 2] * (1.f / 65536.f);
    float msq = stats[(b * 8 + h) * 2 + 1] * (1.f / 65536.f);
    float rinv = rsqrtf(msq - mean * mean + 1e-5f);
    size_t off_ = (size_t)row * DM + dpair;
    float2 vv = *(const float2*)&ctx[off_];
    bf16x2 o;
    o[0] = (__bf16)(((vv.x - mean) * rinv * gamma[dpair] + beta[dpair]) * 0.8f);
    o[1] = (__bf16)(((vv.y - mean) * rinv * gamma[dpair + 1] + beta[dpair + 1]) * 0.8f);
    *(bf16x2*)&out[off_] = o;
}

// ---------------------------------------------------------------------------
extern "C" void kernel_launch(void* const* d_in, const int* in_sizes, int n_in,
                              void* d_out, int out_size, void* d_ws, size_t ws_size,
                              hipStream_t stream) {
    const float* x        = (const float*)d_in[0];
    const int*   mask     = (const int*)d_in[1];
    const float* lam      = (const float*)d_in[2];
    const float* wq_w     = (const float*)d_in[3];
    const float* wq_b     = (const float*)d_in[4];
    const float* wk_w     = (const float*)d_in[5];
    const float* wk_b     = (const float*)d_in[6];
    const float* wv_w     = (const float*)d_in[7];
    const float* wv_b     = (const float*)d_in[8];
    const float* out_w    = (const float*)d_in[9];
    const float* out_b    = (const float*)d_in[10];
    const float* gn_gamma = (const float*)d_in[11];
    const float* gn_beta  = (const float*)d_in[12];
    const float* aq_w     = (const float*)d_in[13];
    const float* aq_b     = (const float*)d_in[14];
    const float* ak_w     = (const float*)d_in[15];
    const float* ak_b     = (const float*)d_in[16];
    const float* wg_w     = (const float*)d_in[17];
    const float* w1_w     = (const float*)d_in[18];
    const float* w2_w     = (const float*)d_in[19];
    const float* norm1_w  = (const float*)d_in[20];
    const float* norm2_w  = (const float*)d_in[21];

    char* ws = (char*)d_ws;
    __bf16* aqkT = (__bf16*)(ws + 0);            // [1024][512]  1MB
    __bf16* qkvT = (__bf16*)(ws + 1 * MB);       // [2560][512]  2.5MB
    __bf16* outT = (__bf16*)(ws + 7 * MB / 2);   // [512][512]   0.5MB
    __bf16* wgT  = (__bf16*)(ws + 4 * MB);       // [2048][512]  2MB
    __bf16* w1T  = (__bf16*)(ws + 6 * MB);       // 2MB
    __bf16* w2T  = (__bf16*)(ws + 8 * MB);       // [512][2048]  2MB
    __bf16* xn   = (__bf16*)(ws + 10 * MB);      // [4096][512]  4MB
    __bf16* aqk  = (__bf16*)(ws + 14 * MB);      // [4096][1024] 8MB
    __bf16* qkv  = (__bf16*)(ws + 22 * MB);      // [4096][2560] 20MB
    float*  la   = (float*)(ws + 42 * MB);
    float*  Lb   = (float*)(ws + 42 * MB + 64 * 1024);
    float*  stats= (float*)(ws + 42 * MB + 128 * 1024);   // 64 floats
    float*  aqk_b= (float*)(ws + 42 * MB + 192 * 1024);
    float*  qkv_b= (float*)(ws + 42 * MB + 256 * 1024);
    float*  ctx  = (float*)(ws + 43 * MB);       // 8MB
    __bf16* ctxb = (__bf16*)(ws + 51 * MB);      // 4MB
    float*  h    = (float*)(ws + 55 * MB);       // 8MB
    __bf16* hn   = (__bf16*)(ws + 14 * MB);      // reuse aqk
    __bf16* mid  = (__bf16*)(ws + 22 * MB);      // reuse qkv
    float*  outp = (float*)d_out;

    const int M = Bn * Sn;  // 4096
    dim3 thr(32, 8);

    hipMemsetAsync(stats, 0, 64 * sizeof(float), stream);

    TransBatch ta = {{aq_w, ak_w, wv_w, out_w},
                     {aqkT, aqkT + 512 * 512, qkvT + (size_t)2048 * 512, outT}};
    transpose_kernel<<<dim3(16, 16, 4), thr, 0, stream>>>(ta, 512, 512);
    TransBatch tbq = {{wq_w, wk_w, nullptr, nullptr},
                      {qkvT, qkvT + (size_t)1024 * 512, nullptr, nullptr}};
    transpose_kernel<<<dim3(32, 16, 2), thr, 0, stream>>>(tbq, 512, 1024);
    TransBatch tc = {{wg_w, w1_w, nullptr, nullptr}, {wgT, w1T, nullptr, nullptr}};
    transpose_kernel<<<dim3(64, 16, 2), thr, 0, stream>>>(tc, 512, 2048);
    TransBatch td = {{w2_w, nullptr, nullptr, nullptr}, {w2T, nullptr, nullptr, nullptr}};
    transpose_kernel<<<dim3(16, 64, 1), thr, 0, stream>>>(td, 2048, 512);

    pack_biases<<<14, 256, 0, stream>>>(aq_b, ak_b, wq_b, wk_b, wv_b, aqk_b, qkv_b);

    rmsnorm_kernel<<<M, 256, 0, stream>>>(x, norm1_w, xn);

    gemm_bf16<64, 128, 0><<<dim3(8, 64), 256, 0, stream>>>(xn, aqkT, aqk_b, nullptr, aqk, M, 1024, 512);
    affinity_dots<<<dim3(4, 4), 256, 0, stream>>>(aqk, la);
    scan_kernel<<<Bn, 256, 0, stream>>>(la, Lb);

    gemm_bf16<128, 128, 0><<<dim3(20, 32), 256, 0, stream>>>(xn, qkvT, qkv_b, nullptr, qkv, M, QKVN, 512);

    attn_mfma<<<512, 512, 0, stream>>>(qkv, Lb, mask, lam, ctx);

    gn_stats<<<dim3(32, 8), 256, 0, stream>>>(ctx, stats);
    gn_apply<<<M, 256, 0, stream>>>(ctx, stats, gn_gamma, gn_beta, ctxb);

    gemm_bf16<64, 64, 1><<<dim3(8, 64), 256, 0, stream>>>(ctxb, outT, out_b, x, h, M, 512, 512);

    rmsnorm_kernel<<<M, 256, 0, stream>>>(h, norm2_w, hn);

    gemm_swiglu<<<dim3(16, 32), 256, 0, stream>>>(hn, wgT, w1T, mid, M, DFF, 512);

    gemm_bf16<64, 64, 1><<<dim3(8, 64), 256, 0, stream>>>(mid, w2T, nullptr, h, outp, M, 512, DFF);
}

// Round 9
// 315.462 us; speedup vs baseline: 7.3110x; 1.1162x over previous
//
#include <hip/hip_runtime.h>
#include <math.h>

#define Bn 4
#define Sn 1024
#define DM 512
#define NH 8
#define DFF 2048
#define PROJN 3584

typedef __attribute__((ext_vector_type(8))) __bf16 bf16x8;
typedef __attribute__((ext_vector_type(4))) __bf16 bf16x4;
typedef __attribute__((ext_vector_type(2))) __bf16 bf16x2;
typedef __attribute__((ext_vector_type(4))) float f32x4;

#define MB (1u<<20)

// async global->LDS, 16B per lane. dest = wave-uniform base + lane*16.
__device__ __forceinline__ void gl_lds16(const void* g, void* l) {
    __builtin_amdgcn_global_load_lds(
        (const __attribute__((address_space(1))) void*)g,
        (__attribute__((address_space(3))) void*)l, 16, 0, 0);
}

// ---------------------------------------------------------------------------
// batched transpose + f32->bf16: dst[n][k] = src[k][n]
// ---------------------------------------------------------------------------
struct TransBatch { const float* src[4]; __bf16* dst[4]; };

__global__ __launch_bounds__(256)
void transpose_kernel(TransBatch tb, int K, int N) {
    const float* w = tb.src[blockIdx.z];
    __bf16* wT = tb.dst[blockIdx.z];
    __shared__ float tile[32][33];
    int n0 = blockIdx.x * 32, k0 = blockIdx.y * 32;
    int tx = threadIdx.x, ty = threadIdx.y;  // 32 x 8
#pragma unroll
    for (int i = 0; i < 4; ++i)
        tile[ty + 8 * i][tx] = w[(size_t)(k0 + ty + 8 * i) * N + n0 + tx];
    __syncthreads();
#pragma unroll
    for (int i = 0; i < 4; ++i)
        wT[(size_t)(n0 + ty + 8 * i) * K + k0 + tx] = (__bf16)tile[tx][ty + 8 * i];
}

// pack proj biases: [3584] = aq_b|ak_b|wq_b|wk_b|wv_b
__global__ __launch_bounds__(256)
void pack_biases(const float* aq_b, const float* ak_b, const float* wq_b,
                 const float* wk_b, const float* wv_b, float* proj_b) {
    int t = blockIdx.x * 256 + threadIdx.x;
    if (t < 512) proj_b[t] = aq_b[t];
    else if (t < 1024) proj_b[t] = ak_b[t - 512];
    else if (t < 2048) proj_b[t] = wq_b[t - 1024];
    else if (t < 3072) proj_b[t] = wk_b[t - 2048];
    else if (t < 3584) proj_b[t] = wv_b[t - 3072];
}

// ---------------------------------------------------------------------------
// RMSNorm: f32 in -> bf16 out. one block per row.
// ---------------------------------------------------------------------------
__global__ __launch_bounds__(256)
void rmsnorm_kernel(const float* __restrict__ x, const float* __restrict__ w,
                    __bf16* __restrict__ out) {
    int row = blockIdx.x;
    const float* xr = x + (size_t)row * DM;
    int t = threadIdx.x;
    float2 v = *(const float2*)&xr[2 * t];
    float ss = v.x * v.x + v.y * v.y;
#pragma unroll
    for (int off = 32; off; off >>= 1) ss += __shfl_xor(ss, off);
    __shared__ float red[4];
    int wid = t >> 6;
    if ((t & 63) == 0) red[wid] = ss;
    __syncthreads();
    float tot = red[0] + red[1] + red[2] + red[3];
    float rinv = rsqrtf(tot / (float)DM + 1e-5f);
    bf16x2 o;
    o[0] = (__bf16)(v.x * rinv * w[2 * t]);
    o[1] = (__bf16)(v.y * rinv * w[2 * t + 1]);
    *(bf16x2*)&out[(size_t)row * DM + 2 * t] = o;
}

// ---------------------------------------------------------------------------
// bf16 MFMA GEMM, global_load_lds staging, source-preswizzled LDS.
// out[M,N] = A[M,K] @ BT[N,K]^T (+bias) (+res). BK=32, 4 waves 2x2.
// ---------------------------------------------------------------------------
template<int BM, int BN, int EPI>
__global__ __launch_bounds__(256)
void gemm_bf16(const __bf16* __restrict__ A, const __bf16* __restrict__ BT,
               const float* __restrict__ bias, const float* __restrict__ res,
               void* __restrict__ out, int M, int N, int K) {
    __shared__ __align__(16) char AsB[BM * 64];
    __shared__ __align__(16) char BsB[BN * 64];
    const int t = threadIdx.x;
    const int w = t >> 6, l = t & 63, c = l & 15, g = l >> 4;
    const int wr = w >> 1, wc = w & 1;
    const int bm = blockIdx.y * BM, bn = blockIdx.x * BN;
    constexpr int HM = BM / 2, WM = BM / 32, HN = BN / 2, WN = BN / 32;
    f32x4 acc[WM][WN];
#pragma unroll
    for (int m = 0; m < WM; ++m)
#pragma unroll
        for (int n = 0; n < WN; ++n) acc[m][n] = (f32x4){0.f, 0.f, 0.f, 0.f};
    const int srow = t >> 2;
    const int kcol = ((t & 3) ^ ((t >> 3) & 3)) << 3;
    const __bf16* Ap = A + (size_t)(bm + srow) * K + kcol;
    const __bf16* Bp = BT + (size_t)(bn + srow) * K + kcol;
    const int sw = (g ^ ((c >> 1) & 3)) << 4;
    for (int k0 = 0; k0 < K; k0 += 32) {
        gl_lds16(Ap + k0, AsB + t * 16);
        if constexpr (BM == 128) gl_lds16(Ap + (size_t)64 * K + k0, AsB + 4096 + t * 16);
        gl_lds16(Bp + k0, BsB + t * 16);
        if constexpr (BN == 128) gl_lds16(Bp + (size_t)64 * K + k0, BsB + 4096 + t * 16);
        __syncthreads();
        bf16x8 af[WM], bf_[WN];
#pragma unroll
        for (int m = 0; m < WM; ++m)
            af[m] = *(const bf16x8*)(AsB + (wr * HM + m * 16 + c) * 64 + sw);
#pragma unroll
        for (int n = 0; n < WN; ++n)
            bf_[n] = *(const bf16x8*)(BsB + (wc * HN + n * 16 + c) * 64 + sw);
#pragma unroll
        for (int m = 0; m < WM; ++m)
#pragma unroll
            for (int n = 0; n < WN; ++n)
                acc[m][n] = __builtin_amdgcn_mfma_f32_16x16x32_bf16(af[m], bf_[n], acc[m][n], 0, 0, 0);
        __syncthreads();
    }
#pragma unroll
    for (int m = 0; m < WM; ++m)
#pragma unroll
        for (int n = 0; n < WN; ++n) {
            int rowb = bm + wr * HM + m * 16 + 4 * g;
            int col = bn + wc * HN + n * 16 + c;
            float bv = bias ? bias[col] : 0.f;
#pragma unroll
            for (int r = 0; r < 4; ++r) {
                size_t idx = (size_t)(rowb + r) * N + col;
                float val = acc[m][n][r] + bv;
                if constexpr (EPI == 0) {
                    ((__bf16*)out)[idx] = (__bf16)val;
                } else {
                    if (res) val += res[idx];
                    ((float*)out)[idx] = val;
                }
            }
        }
}

// ---------------------------------------------------------------------------
// merged projection GEMM: proj[M,3584] = xn @ projT^T + proj_b.
// cols 0..3071 -> proj buffer (bf16); cols 3072..3583 (V) -> vT[d][token].
// ---------------------------------------------------------------------------
__global__ __launch_bounds__(256)
void gemm_proj(const __bf16* __restrict__ A, const __bf16* __restrict__ BT,
               const float* __restrict__ bias, __bf16* __restrict__ out,
               __bf16* __restrict__ vT, int M, int N, int K) {
    __shared__ __align__(16) char AsB[128 * 64];
    __shared__ __align__(16) char BsB[128 * 64];
    const int t = threadIdx.x;
    const int w = t >> 6, l = t & 63, c = l & 15, g = l >> 4;
    const int wr = w >> 1, wc = w & 1;
    const int bm = blockIdx.y * 128, bn = blockIdx.x * 128;
    f32x4 acc[4][4];
#pragma unroll
    for (int m = 0; m < 4; ++m)
#pragma unroll
        for (int n = 0; n < 4; ++n) acc[m][n] = (f32x4){0.f, 0.f, 0.f, 0.f};
    const int srow = t >> 2;
    const int kcol = ((t & 3) ^ ((t >> 3) & 3)) << 3;
    const __bf16* Ap = A + (size_t)(bm + srow) * K + kcol;
    const __bf16* Bp = BT + (size_t)(bn + srow) * K + kcol;
    const int sw = (g ^ ((c >> 1) & 3)) << 4;
    for (int k0 = 0; k0 < K; k0 += 32) {
        gl_lds16(Ap + k0, AsB + t * 16);
        gl_lds16(Ap + (size_t)64 * K + k0, AsB + 4096 + t * 16);
        gl_lds16(Bp + k0, BsB + t * 16);
        gl_lds16(Bp + (size_t)64 * K + k0, BsB + 4096 + t * 16);
        __syncthreads();
        bf16x8 af[4], bf_[4];
#pragma unroll
        for (int m = 0; m < 4; ++m)
            af[m] = *(const bf16x8*)(AsB + (wr * 64 + m * 16 + c) * 64 + sw);
#pragma unroll
        for (int n = 0; n < 4; ++n)
            bf_[n] = *(const bf16x8*)(BsB + (wc * 64 + n * 16 + c) * 64 + sw);
#pragma unroll
        for (int m = 0; m < 4; ++m)
#pragma unroll
            for (int n = 0; n < 4; ++n)
                acc[m][n] = __builtin_amdgcn_mfma_f32_16x16x32_bf16(af[m], bf_[n], acc[m][n], 0, 0, 0);
        __syncthreads();
    }
    if (bn < 3072) {
#pragma unroll
        for (int m = 0; m < 4; ++m)
#pragma unroll
            for (int n = 0; n < 4; ++n) {
                int rowb = bm + wr * 64 + m * 16 + 4 * g;
                int col = bn + wc * 64 + n * 16 + c;
                float bv = bias[col];
#pragma unroll
                for (int r = 0; r < 4; ++r)
                    out[(size_t)(rowb + r) * N + col] = (__bf16)(acc[m][n][r] + bv);
            }
    } else {
        // V block: write transposed vT[d][token], 4 tokens packed per store
#pragma unroll
        for (int m = 0; m < 4; ++m)
#pragma unroll
            for (int n = 0; n < 4; ++n) {
                int rowb = bm + wr * 64 + m * 16 + 4 * g;
                int col = bn + wc * 64 + n * 16 + c;
                float bv = bias[col];
                int d = col - 3072;
                bf16x4 pk;
#pragma unroll
                for (int r = 0; r < 4; ++r) pk[r] = (__bf16)(acc[m][n][r] + bv);
                *(bf16x4*)(vT + (size_t)d * 4096 + rowb) = pk;
            }
    }
}

// ---------------------------------------------------------------------------
// SwiGLU GEMM: mid = silu(A@GT^T) * (A@UT^T), bf16 out. 128x128.
// ---------------------------------------------------------------------------
__global__ __launch_bounds__(256)
void gemm_swiglu(const __bf16* __restrict__ A, const __bf16* __restrict__ GT,
                 const __bf16* __restrict__ UT, __bf16* __restrict__ out,
                 int M, int N, int K) {
    __shared__ __align__(16) char AsB[128 * 64];
    __shared__ __align__(16) char GsB[128 * 64];
    __shared__ __align__(16) char UsB[128 * 64];
    const int t = threadIdx.x;
    const int w = t >> 6, l = t & 63, c = l & 15, g = l >> 4;
    const int wr = w >> 1, wc = w & 1;
    const int bm = blockIdx.y * 128, bn = blockIdx.x * 128;
    f32x4 accg[4][4], accu[4][4];
#pragma unroll
    for (int m = 0; m < 4; ++m)
#pragma unroll
        for (int n = 0; n < 4; ++n) {
            accg[m][n] = (f32x4){0.f, 0.f, 0.f, 0.f};
            accu[m][n] = (f32x4){0.f, 0.f, 0.f, 0.f};
        }
    const int srow = t >> 2;
    const int kcol = ((t & 3) ^ ((t >> 3) & 3)) << 3;
    const __bf16* Ap = A + (size_t)(bm + srow) * K + kcol;
    const __bf16* Gp = GT + (size_t)(bn + srow) * K + kcol;
    const __bf16* Up = UT + (size_t)(bn + srow) * K + kcol;
    const int sw = (g ^ ((c >> 1) & 3)) << 4;
    for (int k0 = 0; k0 < K; k0 += 32) {
        gl_lds16(Ap + k0, AsB + t * 16);
        gl_lds16(Ap + (size_t)64 * K + k0, AsB + 4096 + t * 16);
        gl_lds16(Gp + k0, GsB + t * 16);
        gl_lds16(Gp + (size_t)64 * K + k0, GsB + 4096 + t * 16);
        gl_lds16(Up + k0, UsB + t * 16);
        gl_lds16(Up + (size_t)64 * K + k0, UsB + 4096 + t * 16);
        __syncthreads();
        bf16x8 af[4], gf[4], uf[4];
#pragma unroll
        for (int m = 0; m < 4; ++m)
            af[m] = *(const bf16x8*)(AsB + (wr * 64 + m * 16 + c) * 64 + sw);
#pragma unroll
        for (int n = 0; n < 4; ++n) {
            gf[n] = *(const bf16x8*)(GsB + (wc * 64 + n * 16 + c) * 64 + sw);
            uf[n] = *(const bf16x8*)(UsB + (wc * 64 + n * 16 + c) * 64 + sw);
        }
#pragma unroll
        for (int m = 0; m < 4; ++m)
#pragma unroll
            for (int n = 0; n < 4; ++n) {
                accg[m][n] = __builtin_amdgcn_mfma_f32_16x16x32_bf16(af[m], gf[n], accg[m][n], 0, 0, 0);
                accu[m][n] = __builtin_amdgcn_mfma_f32_16x16x32_bf16(af[m], uf[n], accu[m][n], 0, 0, 0);
            }
        __syncthreads();
    }
#pragma unroll
    for (int m = 0; m < 4; ++m)
#pragma unroll
        for (int n = 0; n < 4; ++n) {
            int rowb = bm + wr * 64 + m * 16 + 4 * g;
            int col = bn + wc * 64 + n * 16 + c;
#pragma unroll
            for (int r = 0; r < 4; ++r) {
                float gv = accg[m][n][r];
                float uv = accu[m][n][r];
                float sg = gv / (1.f + __expf(-gv));
                out[(size_t)(rowb + r) * N + col] = (__bf16)(sg * uv);
            }
        }
}

// ---------------------------------------------------------------------------
// neighbor affinity log a — one wave per i. proj cols 0..511 = Q, 512..1023 = K.
// ---------------------------------------------------------------------------
__global__ __launch_bounds__(256)
void affinity_dots(const __bf16* __restrict__ proj, float* __restrict__ la) {
    int b = blockIdx.y;
    int i = blockIdx.x * 4 + (threadIdx.x >> 6);
    int l = threadIdx.x & 63;
    if (i >= Sn - 1) { if (l == 0 && i < Sn) la[b * Sn + i] = 0.f; return; }
    const __bf16* Qi  = proj + (size_t)(b * Sn + i) * PROJN;
    const __bf16* Ki  = Qi + 512;
    const __bf16* Qi1 = Qi + PROJN;
    const __bf16* Ki1 = Ki + PROJN;
    bf16x8 q0 = *(const bf16x8*)(Qi + l * 8);
    bf16x8 k1 = *(const bf16x8*)(Ki1 + l * 8);
    bf16x8 q1 = *(const bf16x8*)(Qi1 + l * 8);
    bf16x8 k0 = *(const bf16x8*)(Ki + l * 8);
    float sf = 0.f, sb = 0.f;
#pragma unroll
    for (int j = 0; j < 8; ++j) {
        sf += (float)q0[j] * (float)k1[j];
        sb += (float)q1[j] * (float)k0[j];
    }
#pragma unroll
    for (int off = 32; off; off >>= 1) {
        sf += __shfl_xor(sf, off);
        sb += __shfl_xor(sb, off);
    }
    if (l == 0) {
        sf *= (1.f / 512.f);
        sb *= (1.f / 512.f);
        float a = 0.5f * (1.f / (1.f + __expf(-sf)) + 1.f / (1.f + __expf(-sb)));
        la[b * Sn + i] = __logf(a);
    }
}

// inclusive-scan of log-a -> L. one block (256 thr) per batch.
__global__ __launch_bounds__(256)
void scan_kernel(const float* __restrict__ la, float* __restrict__ L) {
    int b = blockIdx.x, j = threadIdx.x;
    __shared__ float sc[256];
    float4 v = *(const float4*)&la[b * Sn + 4 * j];
    float s0 = v.x, s1 = s0 + v.y, s2 = s1 + v.z, s3 = s2 + v.w;
    sc[j] = s3;
    __syncthreads();
    for (int off = 1; off < 256; off <<= 1) {
        float add = (j >= off) ? sc[j - off] : 0.f;
        __syncthreads();
        sc[j] += add;
        __syncthreads();
    }
    float base = sc[j] - s3;
    if (j == 0) L[b * Sn] = 0.f;
    L[b * Sn + 4 * j + 1] = base + s0;
    L[b * Sn + 4 * j + 2] = base + s1;
    L[b * Sn + 4 * j + 3] = base + s2;
    if (4 * j + 4 < Sn) L[b * Sn + 4 * j + 4] = base + s3;
}

// ---------------------------------------------------------------------------
// Flash-style differential attention. 8 waves: 0-3 mat0, 4-7 mat1.
// K and pre-transposed V staged via gl_lds (preswizzled source); 2 barriers/tile.
// ---------------------------------------------------------------------------
__global__ __launch_bounds__(512)
void attn_mfma(const __bf16* __restrict__ proj, const __bf16* __restrict__ vT,
               const float* __restrict__ L, const int* __restrict__ mask,
               const float* __restrict__ lam_p, float* __restrict__ ctx) {
    // linear grid 512; keep all 16 q-blocks of one (b,h) on one XCD
    int x = blockIdx.x;
    int xcd = x & 7, idx = x >> 3;
    int bh = xcd * 4 + (idx >> 4);   // 0..31
    int qb = idx & 15;
    int b = bh >> 3, h = bh & 7;
    const int t = threadIdx.x;
    const int w = t >> 6, l = t & 63, c = l & 15, g = l >> 4;
    const int mat = w >> 2, ws = w & 3;

    __shared__ __align__(16) char KldsB[64 * 256];      // [k][16 grp]: 0-7 mat0, 8-15 mat1; swz ^(k&7)
    __shared__ __align__(16) char VtB[64 * 128];        // [d][8 grp of k], swz ^(d&7)
    __shared__ __align__(16) char PldsB[2][64 * 128];   // [q][8 grp of k], swz ^(q&7); f32 reuse at end
    __shared__ float Lk_s[64];
    __shared__ float msk_s[64];
    __shared__ float fs_s[2][64];
    __shared__ float ls_s[2][64];

    const int q0 = qb * 64;
    const int qg = q0 + 16 * ws + c;
    float Lq = L[b * Sn + qg];
    float lam = lam_p[0];
    bf16x8 qf[2];
#pragma unroll
    for (int dh = 0; dh < 2; ++dh)
        qf[dh] = *(const bf16x8*)(proj + (size_t)(b * Sn + qg) * PROJN + 1024 + mat * 512 + h * 64 + dh * 32 + g * 8);
    f32x4 O[4];
#pragma unroll
    for (int nd = 0; nd < 4; ++nd) O[nd] = (f32x4){0.f, 0.f, 0.f, 0.f};
    float m_run = -INFINITY;
    float l_run = 0.f;
    const int cs = c & 7;

    for (int kt = 0; kt < 16; ++kt) {
        const int ktok = b * Sn + kt * 64;
        // ---- K via gl_lds (both mats), source preswizzled ----
#pragma unroll
        for (int rep = 0; rep < 2; ++rep) {
            int u = t & 255;
            int rr = (t >> 8) + 2 * rep;
            int krow = rr * 16 + (u >> 4);
            int km = (u >> 3) & 1;
            int lg = (u & 7) ^ (krow & 7);
            gl_lds16(proj + (size_t)(ktok + krow) * PROJN + 2048 + km * 512 + h * 64 + lg * 8,
                     KldsB + rr * 4096 + u * 16);
        }
        // ---- V^T via gl_lds (one shot), source preswizzled ----
        {
            int row = t >> 3;
            int lg = (t & 7) ^ (row & 7);
            gl_lds16(vT + (size_t)(h * 64 + row) * 4096 + ktok + lg * 8, VtB + t * 16);
        }
        if (t < 64) {
            Lk_s[t] = L[ktok + t];
            msk_s[t] = (float)mask[ktok + t];
        }
        __syncthreads();
        // ---- hoisted per-k C and mask bits ----
        float Cv[16];
        unsigned mbits = 0;
#pragma unroll
        for (int kf = 0; kf < 4; ++kf)
#pragma unroll
            for (int r = 0; r < 4; ++r) {
                int kk = kf * 16 + 4 * g + r;
                Cv[kf * 4 + r] = __expf(-fabsf(Lq - Lk_s[kk]));
                mbits |= (msk_s[kk] != 0.f ? 1u : 0u) << (kf * 4 + r);
            }
        // ---- QK^T (swapped) for own mat ----
        f32x4 s[4];
        __builtin_amdgcn_s_setprio(1);
#pragma unroll
        for (int kf = 0; kf < 4; ++kf) {
            f32x4 a = (f32x4){0.f, 0.f, 0.f, 0.f};
#pragma unroll
            for (int dh = 0; dh < 2; ++dh) {
                bf16x8 kfr = *(const bf16x8*)(KldsB + (kf * 16 + c) * 256 + (mat * 8 + ((dh * 4 + g) ^ cs)) * 16);
                a = __builtin_amdgcn_mfma_f32_16x16x32_bf16(kfr, qf[dh], a, 0, 0, 0);
            }
            s[kf] = a;
        }
        __builtin_amdgcn_s_setprio(0);
        // ---- online softmax ----
        float tm = -INFINITY;
#pragma unroll
        for (int kf = 0; kf < 4; ++kf)
#pragma unroll
            for (int r = 0; r < 4; ++r) {
                float sv = ((mbits >> (kf * 4 + r)) & 1u) ? s[kf][r] * 0.125f : -1e9f;
                s[kf][r] = sv;
                tm = fmaxf(tm, sv);
            }
        tm = fmaxf(tm, __shfl_xor(tm, 16));
        tm = fmaxf(tm, __shfl_xor(tm, 32));
        float mn = fmaxf(m_run, tm);
        float f = __expf(m_run - mn);
        m_run = mn;
        if (g == 0) fs_s[mat][16 * ws + c] = f;
        float es = 0.f;
#pragma unroll
        for (int kf = 0; kf < 4; ++kf) {
            bf16x2 p01, p23;
            float e0 = __expf(s[kf][0] - mn);
            float e1 = __expf(s[kf][1] - mn);
            float e2 = __expf(s[kf][2] - mn);
            float e3 = __expf(s[kf][3] - mn);
            es += (e0 + e1) + (e2 + e3);
            p01[0] = (__bf16)(e0 * Cv[kf * 4 + 0]);
            p01[1] = (__bf16)(e1 * Cv[kf * 4 + 1]);
            p23[0] = (__bf16)(e2 * Cv[kf * 4 + 2]);
            p23[1] = (__bf16)(e3 * Cv[kf * 4 + 3]);
            char* pb = PldsB[mat] + (16 * ws + c) * 128 + (((kf * 2 + (g >> 1)) ^ cs) << 4) + ((g & 1) << 3);
            *(bf16x2*)pb = p01;
            *(bf16x2*)(pb + 4) = p23;
        }
        es += __shfl_xor(es, 16);
        es += __shfl_xor(es, 32);
        l_run = l_run * f + es;
        // (no barrier: P/fs written and read by the same wave)
        // ---- PV for own mat ----
        f32x4 fv = *(const f32x4*)&fs_s[mat][16 * ws + 4 * g];
#pragma unroll
        for (int nd = 0; nd < 4; ++nd) O[nd] *= fv;
        __builtin_amdgcn_s_setprio(1);
#pragma unroll
        for (int kh = 0; kh < 2; ++kh) {
            bf16x8 pa = *(const bf16x8*)(PldsB[mat] + (16 * ws + c) * 128 + (((kh * 4 + g) ^ cs) << 4));
#pragma unroll
            for (int nd = 0; nd < 4; ++nd) {
                bf16x8 vb = *(const bf16x8*)(VtB + (nd * 16 + c) * 128 + (((kh * 4 + g) ^ cs) << 4));
                O[nd] = __builtin_amdgcn_mfma_f32_16x16x32_bf16(pa, vb, O[nd], 0, 0, 0);
            }
        }
        __builtin_amdgcn_s_setprio(0);
        __syncthreads();   // protect K/Vt overwrite next tile
    }
    if (g == 0) ls_s[mat][16 * ws + c] = l_run;
    __syncthreads();
    f32x4 lv = *(const f32x4*)&ls_s[mat][16 * ws + 4 * g];
#pragma unroll
    for (int nd = 0; nd < 4; ++nd)
#pragma unroll
        for (int r = 0; r < 4; ++r) O[nd][r] /= lv[r];
    float* Pf = (float*)PldsB;
    if (mat == 1) {
#pragma unroll
        for (int nd = 0; nd < 4; ++nd)
#pragma unroll
            for (int r = 0; r < 4; ++r)
                Pf[(16 * ws + 4 * g + r) * 64 + nd * 16 + c] = O[nd][r];
    }
    __syncthreads();
    if (mat == 0) {
#pragma unroll
        for (int nd = 0; nd < 4; ++nd)
#pragma unroll
            for (int r = 0; r < 4; ++r) {
                float val = O[nd][r] - lam * Pf[(16 * ws + 4 * g + r) * 64 + nd * 16 + c];
                int q = q0 + 16 * ws + 4 * g + r;
                ctx[(size_t)(b * Sn + q) * DM + h * 64 + nd * 16 + c] = val;
            }
    }
}

// ---------------------------------------------------------------------------
// GroupNorm split: stats (atomic partial sums) + apply
// ---------------------------------------------------------------------------
__global__ __launch_bounds__(256)
void gn_stats(const float* __restrict__ ctx, float* __restrict__ stats) {
    int b = blockIdx.x >> 3, h = blockIdx.x & 7;
    int s0 = blockIdx.y * 128;
    int t = threadIdx.x;
    float sum = 0.f, sq = 0.f;
    for (int i = t; i < 128 * 32; i += 256) {
        int s = s0 + (i >> 5), dp = (i & 31) * 2;
        float2 vv = *(const float2*)&ctx[(size_t)(b * Sn + s) * DM + h * 64 + dp];
        sum += vv.x + vv.y;
        sq += vv.x * vv.x + vv.y * vv.y;
    }
#pragma unroll
    for (int off = 32; off; off >>= 1) {
        sum += __shfl_xor(sum, off);
        sq += __shfl_xor(sq, off);
    }
    __shared__ float rs[4], rq[4];
    int wid = t >> 6;
    if ((t & 63) == 0) { rs[wid] = sum; rq[wid] = sq; }
    __syncthreads();
    if (t == 0) {
        atomicAdd(&stats[blockIdx.x * 2], rs[0] + rs[1] + rs[2] + rs[3]);
        atomicAdd(&stats[blockIdx.x * 2 + 1], rq[0] + rq[1] + rq[2] + rq[3]);
    }
}

__global__ __launch_bounds__(256)
void gn_apply(const float* __restrict__ ctx, const float* __restrict__ stats,
              const float* __restrict__ gamma, const float* __restrict__ beta,
              __bf16* __restrict__ out) {
    int row = blockIdx.x;               // b*Sn + s
    int b = row >> 10;
    int t = threadIdx.x;
    int dpair = t * 2;                  // 0..511
    int h = dpair >> 6;
    float mean = stats[(b * 8 + h) * 2] * (1.f / 65536.f);
    float msq = stats[(b * 8 + h) * 2 + 1] * (1.f / 65536.f);
    float rinv = rsqrtf(msq - mean * mean + 1e-5f);
    size_t off_ = (size_t)row * DM + dpair;
    float2 vv = *(const float2*)&ctx[off_];
    bf16x2 o;
    o[0] = (__bf16)(((vv.x - mean) * rinv * gamma[dpair] + beta[dpair]) * 0.8f);
    o[1] = (__bf16)(((vv.y - mean) * rinv * gamma[dpair + 1] + beta[dpair + 1]) * 0.8f);
    *(bf16x2*)&out[off_] = o;
}

// ---------------------------------------------------------------------------
extern "C" void kernel_launch(void* const* d_in, const int* in_sizes, int n_in,
                              void* d_out, int out_size, void* d_ws, size_t ws_size,
                              hipStream_t stream) {
    const float* x        = (const float*)d_in[0];
    const int*   mask     = (const int*)d_in[1];
    const float* lam      = (const float*)d_in[2];
    const float* wq_w     = (const float*)d_in[3];
    const float* wq_b     = (const float*)d_in[4];
    const float* wk_w     = (const float*)d_in[5];
    const float* wk_b     = (const float*)d_in[6];
    const float* wv_w     = (const float*)d_in[7];
    const float* wv_b     = (const float*)d_in[8];
    const float* out_w    = (const float*)d_in[9];
    const float* out_b    = (const float*)d_in[10];
    const float* gn_gamma = (const float*)d_in[11];
    const float* gn_beta  = (const float*)d_in[12];
    const float* aq_w     = (const float*)d_in[13];
    const float* aq_b     = (const float*)d_in[14];
    const float* ak_w     = (const float*)d_in[15];
    const float* ak_b     = (const float*)d_in[16];
    const float* wg_w     = (const float*)d_in[17];
    const float* w1_w     = (const float*)d_in[18];
    const float* w2_w     = (const float*)d_in[19];
    const float* norm1_w  = (const float*)d_in[20];
    const float* norm2_w  = (const float*)d_in[21];

    char* ws = (char*)d_ws;
    __bf16* projT = (__bf16*)(ws + 0);            // [3584][512]  3.5MB
    __bf16* outT  = (__bf16*)(ws + 7 * MB / 2);   // [512][512]   0.5MB
    __bf16* wgT   = (__bf16*)(ws + 4 * MB);       // 2MB
    __bf16* w1T   = (__bf16*)(ws + 6 * MB);       // 2MB
    __bf16* w2T   = (__bf16*)(ws + 8 * MB);       // 2MB
    __bf16* xn    = (__bf16*)(ws + 10 * MB);      // 4MB  (reused: ctxb)
    __bf16* proj  = (__bf16*)(ws + 14 * MB);      // [4096][3584] 28MB (reused: mid)
    __bf16* vT    = (__bf16*)(ws + 42 * MB);      // [512][4096]  4MB  (reused: hn)
    float*  la    = (float*)(ws + 46 * MB);
    float*  Lb    = (float*)(ws + 46 * MB + 64 * 1024);
    float*  stats = (float*)(ws + 46 * MB + 128 * 1024);
    float*  proj_b= (float*)(ws + 46 * MB + 192 * 1024);  // 14KB
    float*  ctx   = (float*)(ws + 47 * MB);       // 8MB
    float*  h     = (float*)(ws + 55 * MB);       // 8MB
    __bf16* ctxb  = (__bf16*)(ws + 10 * MB);      // reuse xn
    __bf16* mid   = (__bf16*)(ws + 14 * MB);      // reuse proj
    __bf16* hn    = (__bf16*)(ws + 42 * MB);      // reuse vT
    float*  outp  = (float*)d_out;

    const int M = Bn * Sn;  // 4096
    dim3 thr(32, 8);

    hipMemsetAsync(stats, 0, 64 * sizeof(float), stream);

    TransBatch ta = {{aq_w, ak_w, wv_w, out_w},
                     {projT, projT + 512 * 512, projT + (size_t)3072 * 512, outT}};
    transpose_kernel<<<dim3(16, 16, 4), thr, 0, stream>>>(ta, 512, 512);
    TransBatch tbq = {{wq_w, wk_w, nullptr, nullptr},
                      {projT + (size_t)1024 * 512, projT + (size_t)2048 * 512, nullptr, nullptr}};
    transpose_kernel<<<dim3(32, 16, 2), thr, 0, stream>>>(tbq, 512, 1024);
    TransBatch tc = {{wg_w, w1_w, nullptr, nullptr}, {wgT, w1T, nullptr, nullptr}};
    transpose_kernel<<<dim3(64, 16, 2), thr, 0, stream>>>(tc, 512, 2048);
    TransBatch td = {{w2_w, nullptr, nullptr, nullptr}, {w2T, nullptr, nullptr, nullptr}};
    transpose_kernel<<<dim3(16, 64, 1), thr, 0, stream>>>(td, 2048, 512);

    pack_biases<<<14, 256, 0, stream>>>(aq_b, ak_b, wq_b, wk_b, wv_b, proj_b);

    rmsnorm_kernel<<<M, 256, 0, stream>>>(x, norm1_w, xn);

    gemm_proj<<<dim3(28, 32), 256, 0, stream>>>(xn, projT, proj_b, proj, vT, M, PROJN, 512);

    affinity_dots<<<dim3(256, 4), 256, 0, stream>>>(proj, la);
    scan_kernel<<<Bn, 256, 0, stream>>>(la, Lb);

    attn_mfma<<<512, 512, 0, stream>>>(proj, vT, Lb, mask, lam, ctx);

    gn_stats<<<dim3(32, 8), 256, 0, stream>>>(ctx, stats);
    gn_apply<<<M, 256, 0, stream>>>(ctx, stats, gn_gamma, gn_beta, ctxb);

    gemm_bf16<64, 64, 1><<<dim3(8, 64), 256, 0, stream>>>(ctxb, outT, out_b, x, h, M, 512, 512);

    rmsnorm_kernel<<<M, 256, 0, stream>>>(h, norm2_w, hn);

    gemm_swiglu<<<dim3(16, 32), 256, 0, stream>>>(hn, wgT, w1T, mid, M, DFF, 512);

    gemm_bf16<64, 64, 1><<<dim3(8, 64), 256, 0, stream>>>(mid, w2T, nullptr, h, outp, M, 512, DFF);
}